// Round 4
// baseline (11579.699 us; speedup 1.0000x reference)
//
#include <hip/hip_runtime.h>
#include <hip/hip_bf16.h>
#include <math.h>

#define LSN 2
#define BSN 16
#define NH 256
#define NP 512
#define MIDP 256
#define TTN 16
#define DIN 64
#define NCH 4096
#define GW 1024

__device__ __forceinline__ float sigmoidf_(float x){ return 1.0f/(1.0f+expf(-x)); }

__device__ __forceinline__ float brsum(float v, float* red){
  int tid = threadIdx.x;
  red[tid]=v; __syncthreads();
  for (int s=128; s>0; s>>=1){ if (tid<s) red[tid]+=red[tid+s]; __syncthreads(); }
  float r = red[0]; __syncthreads(); return r;
}

// ---------- prep kernels ----------
__global__ void k_prep_xw0(const float* __restrict__ x, const float* __restrict__ Wih0,
                           const float* __restrict__ b0, float* __restrict__ xW0){
  int row = blockIdx.x; // b*16+t
  __shared__ float xr[DIN];
  if (threadIdx.x < DIN) xr[threadIdx.x] = x[(size_t)row*DIN + threadIdx.x];
  __syncthreads();
  int n = threadIdx.x;
  for (int q=0;q<4;++q){
    int wrow = q*NH + n;
    float acc = b0[wrow];
    #pragma unroll 8
    for (int d=0; d<DIN; ++d) acc += xr[d] * Wih0[(size_t)wrow*DIN + d];
    xW0[(size_t)row*GW + wrow] = acc;
  }
}

__global__ void k_init(const float* __restrict__ part, float* h0, float* h1, float* c0, float* c1){
  int row = blockIdx.x; // l*4096 + b*256 + n
  int i = threadIdx.x;
  int l = row >> 12, b = (row >> 8) & 15, n = row & 255;
  float hv = part[(size_t)row*NP + i];
  float cv = part[(size_t)row*NP + MIDP + i];
  int chain = i*BSN + b;
  if (l==0){ h0[(size_t)chain*NH+n]=hv; c0[(size_t)chain*NH+n]=cv; }
  else     { h1[(size_t)chain*NH+n]=hv; c1[(size_t)chain*NH+n]=cv; }
}

// ---------- simple f32 LSTM step ----------
__global__ __launch_bounds__(256) void k_step_simple(
    const float* __restrict__ A1, const float* __restrict__ A2,
    const float* __restrict__ Wa, const float* __restrict__ Wb,
    const float* __restrict__ xw0, const float* __restrict__ b1,
    float* __restrict__ C, float* __restrict__ Hout,
    int layer, int t, int is_last,
    float* __restrict__ pr, const float* __restrict__ eps_h, const float* __restrict__ eps_c,
    const float* __restrict__ qp, const float* __restrict__ ep)
{
  __shared__ float hs[8][512];
  const int tid = threadIdx.x;
  const int K = (layer == 0) ? 256 : 512;
  const int cbase = blockIdx.x * 8;

  for (int idx = tid; idx < 8*K; idx += 256) {
    int cc = idx / K, k = idx - cc*K;
    int chain = cbase + cc;
    float v = (k < 256) ? A1[(size_t)chain*NH + k] : A2[(size_t)chain*NH + (k-256)];
    hs[cc][k] = v;
  }
  __syncthreads();

  float acc[4][8];
  #pragma unroll
  for (int q=0;q<4;++q)
    #pragma unroll
    for (int cc=0;cc<8;++cc) acc[q][cc] = 0.0f;

  const int n = tid;
  for (int k=0;k<256;++k) {
    float w0 = Wa[(size_t)(0*NH+n)*NH + k];
    float w1 = Wa[(size_t)(1*NH+n)*NH + k];
    float w2 = Wa[(size_t)(2*NH+n)*NH + k];
    float w3 = Wa[(size_t)(3*NH+n)*NH + k];
    #pragma unroll
    for (int cc=0;cc<8;++cc){
      float hv = hs[cc][k];
      acc[0][cc] += w0*hv; acc[1][cc] += w1*hv; acc[2][cc] += w2*hv; acc[3][cc] += w3*hv;
    }
  }
  if (layer == 1) {
    for (int k=0;k<256;++k) {
      float w0 = Wb[(size_t)(0*NH+n)*NH + k];
      float w1 = Wb[(size_t)(1*NH+n)*NH + k];
      float w2 = Wb[(size_t)(2*NH+n)*NH + k];
      float w3 = Wb[(size_t)(3*NH+n)*NH + k];
      #pragma unroll
      for (int cc=0;cc<8;++cc){
        float hv = hs[cc][256+k];
        acc[0][cc] += w0*hv; acc[1][cc] += w1*hv; acc[2][cc] += w2*hv; acc[3][cc] += w3*hv;
      }
    }
  }

  float sq=0.f, se=0.f;
  if (is_last){ sq = sqrtf(qp[0]*qp[0]); se = sqrtf(ep[0]*ep[0]); }

  #pragma unroll
  for (int cc=0;cc<8;++cc){
    int chain = cbase + cc;
    int bb = chain & 15;
    int ip = chain >> 4;
    const float* addp = (layer==0) ? (xw0 + (size_t)(bb*TTN + t)*GW) : b1;
    float gi = acc[0][cc] + addp[0*NH + n];
    float gf = acc[1][cc] + addp[1*NH + n];
    float gg = acc[2][cc] + addp[2*NH + n];
    float go = acc[3][cc] + addp[3*NH + n];
    float cold = C[(size_t)chain*NH + n];
    float c2 = sigmoidf_(gf)*cold + sigmoidf_(gi)*tanhf(gg);
    float h2 = sigmoidf_(go)*tanhf(c2);
    Hout[(size_t)chain*NH + n] = h2;
    if (!is_last) {
      C[(size_t)chain*NH + n] = c2;
    } else {
      size_t rowp = (size_t)(layer*BSN + bb)*NH + n;
      size_t eidx = ((size_t)(ip*LSN + layer)*BSN + bb)*NH + n;
      pr[rowp*NP + ip]        = h2 + sq * eps_h[eidx];
      pr[rowp*NP + MIDP + ip] = c2 + se * eps_c[eidx];
    }
  }
}

// ---------- post kernels ----------
__global__ void k_obs(const float* __restrict__ pr, const float* __restrict__ Wh,
                      const float* __restrict__ bh, float* __restrict__ Y){
  int b = blockIdx.x; int N = blockIdx.y*256 + threadIdx.x;
  float acc = bh[0];
  for (int n=0;n<NH;++n) acc += Wh[n] * pr[((size_t)(BSN + b)*NH + n)*NP + N];
  Y[(size_t)b*NP + N] = acc;
}

__global__ void k_stats1(const float* __restrict__ Y, const float* __restrict__ wts,
                         const float* __restrict__ yv, const float* __restrict__ rp,
                         float* __restrict__ pre){
  int b = blockIdx.x, tid = threadIdx.x;
  __shared__ float red[256];
  float lw0 = logf(wts[b*NP+tid]),     lw1 = logf(wts[b*NP+256+tid]);
  float y0  = Y[b*NP+tid],             y1  = Y[b*NP+256+tid];
  float SW = brsum(lw0+lw1, red);
  float SY = brsum(y0*lw0 + y1*lw1, red);
  float mu = SY/SW;
  float c0=y0-mu, c1=y1-mu;
  float SC = brsum(c0*c0+c1*c1, red);
  float sig = SC/511.0f + rp[0]*rp[0];
  float a = sig+1e-6f, inv = 1.0f/a, ld = logf(a);
  float yb = yv[b];
  float i0 = yb - y0*lw0/SW;
  float i1 = yb - y1*lw1/SW;
  pre[b*NP+tid]     = lw0 - 0.5f*ld - 0.5f*inv*i0*i0;
  pre[b*NP+256+tid] = lw1 - 0.5f*ld - 0.5f*inv*i1*i1;
}

__global__ void k_colsoftmax(const float* __restrict__ pre, float* __restrict__ neww){
  int N = blockIdx.x*256 + threadIdx.x;
  float s=0.f;
  for(int b=0;b<BSN;b++) s += expf(pre[b*NP+N]);
  float ls = logf(s);
  for(int b=0;b<BSN;b++) neww[b*NP+N] = expf(pre[b*NP+N] - ls);
}

__global__ void k_resample(const float* __restrict__ neww, const float* __restrict__ gum,
                           float* __restrict__ wf, int* __restrict__ idxb, int* __restrict__ dofl,
                           float* __restrict__ out){
  int b = blockIdx.x >> 1, hf = blockIdx.x & 1, j = threadIdx.x;
  __shared__ float red[256]; __shared__ float key[256];
  float wh = neww[b*NP + hf*256 + j];
  red[j] = wh*wh; __syncthreads();
  for (int s=128;s>0;s>>=1){ if(j<s) red[j]+=red[j+s]; __syncthreads(); }
  float s2 = red[0]; __syncthreads();
  int doit = (1.0f/s2) < (float)(NP)/4.0f;
  float soft = 0.5f*wh + (0.5f/(float)MIDP);
  float kk = logf(soft) + gum[(b*2+hf)*256 + j];
  key[j] = kk; __syncthreads();
  int rank = 0;
  for (int m=0;m<256;++m){ float km = key[m]; rank += (km > kk) || (km == kk && m < j); }
  idxb[(b*2+hf)*256 + rank] = j;
  float lw = logf(wh/soft);
  red[j] = lw; __syncthreads();
  for (int s=128;s>0;s>>=1){ if(j<s) red[j] = fmaxf(red[j],red[j+s]); __syncthreads(); }
  float mx = red[0]; __syncthreads();
  red[j] = expf(lw-mx); __syncthreads();
  for (int s=128;s>0;s>>=1){ if(j<s) red[j]+=red[j+s]; __syncthreads(); }
  float lse = mx + logf(red[0]);
  float wr = expf(lw - lse);
  float wv = doit ? wr : wh;
  wf[b*NP + hf*256 + j] = wv;
  out[4194336 + b*NP + hf*256 + j] = wv;
  if (j==0) dofl[b*2+hf] = doit;
}

__global__ void k_pfg(const float* __restrict__ pr, const int* __restrict__ idxb,
                      const int* __restrict__ dofl, float* __restrict__ out){
  size_t row = blockIdx.x; // l*4096 + b*256 + n
  int b = (blockIdx.x >> 8) & 15;
  const float* src = pr + row*NP;
  for (int hf=0; hf<2; ++hf){
    int loc = threadIdx.x;
    int N = hf*256 + loc;
    int dcol = dofl[b*2+hf] ? hf*256 + idxb[(b*2+hf)*256 + loc] : N;
    out[32 + row*NP + N] = src[dcol];
  }
}

__global__ void k_yf(const float* __restrict__ Y, const int* __restrict__ idxb,
                     const int* __restrict__ dofl, float* __restrict__ Yf){
  int b = blockIdx.x; int N = threadIdx.x; int hf = N >> 8; int loc = N & 255;
  int dcol = dofl[b*2+hf] ? hf*256 + idxb[(b*2+hf)*256 + loc] : N;
  Yf[b*NP+N] = Y[b*NP+dcol];
}

__global__ void k_final_est(const float* __restrict__ Yf, const float* __restrict__ wf,
                            const float* __restrict__ yv, const float* __restrict__ rp,
                            float* __restrict__ qf, float* __restrict__ ldb,
                            float* __restrict__ out){
  int b = blockIdx.x, tid = threadIdx.x;
  __shared__ float red[256];
  float w0 = wf[b*NP+tid], w1 = wf[b*NP+256+tid];
  float y0 = Yf[b*NP+tid], y1 = Yf[b*NP+256+tid];
  float SW = brsum(w0+w1, red);
  float SY = brsum(y0*w0+y1*w1, red);
  float mu = SY/SW;
  float c0=y0-mu, c1=y1-mu;
  float SC = brsum(c0*c0+c1*c1, red);
  float sig = SC/511.0f + rp[0]*rp[0];
  if (tid==0){
    float a = sig + 1e-6f; float inv = 1.0f/a; float ld = logf(a);
    float inn = yv[b]-mu; float q = inn*inn*inv;
    qf[b]=q; ldb[b]=ld;
    out[b]      = mu;
    out[16 + b] = sig;
  }
}

__global__ void k_final_scalar(const float* __restrict__ qf, const float* __restrict__ ldb,
                               float* __restrict__ out){
  if (threadIdx.x==0){
    float l=0.f, nq=0.f;
    for(int b=0;b<BSN;b++){ l += -0.5f*ldb[b]-0.5f*qf[b]; nq += qf[b]; }
    out[4202528] = l;
    out[4202529] = nq/16.0f;
  }
}

extern "C" void kernel_launch(void* const* d_in, const int* in_sizes, int n_in,
                              void* d_out, int out_size, void* d_ws, size_t ws_size,
                              hipStream_t stream) {
  const float* x      = (const float*)d_in[0];
  const float* yv     = (const float*)d_in[1];
  const float* part   = (const float*)d_in[2];
  const float* wts    = (const float*)d_in[3];
  const float* qp     = (const float*)d_in[4];
  const float* ep     = (const float*)d_in[5];
  const float* rp     = (const float*)d_in[6];
  const float* Wih0   = (const float*)d_in[7];
  const float* Whh0   = (const float*)d_in[8];
  const float* b0     = (const float*)d_in[9];
  const float* Wih1   = (const float*)d_in[10];
  const float* Whh1   = (const float*)d_in[11];
  const float* b1     = (const float*)d_in[12];
  const float* Wh     = (const float*)d_in[13];
  const float* bh     = (const float*)d_in[14];
  const float* eps_h  = (const float*)d_in[15];
  const float* eps_c  = (const float*)d_in[16];
  const float* gum    = (const float*)d_in[17];
  float* out = (float*)d_out;

  char* p = (char*)d_ws;
  float* xW0 = (float*)p; p += (size_t)256*GW*4;
  float* h0A = (float*)p; p += (size_t)NCH*NH*4;
  float* h0B = (float*)p; p += (size_t)NCH*NH*4;
  float* h1A = (float*)p; p += (size_t)NCH*NH*4;
  float* h1B = (float*)p; p += (size_t)NCH*NH*4;
  float* c0  = (float*)p; p += (size_t)NCH*NH*4;
  float* c1  = (float*)p; p += (size_t)NCH*NH*4;
  float* pr  = (float*)p; p += (size_t)LSN*BSN*NH*NP*4;
  float* Yb  = (float*)p; p += 32768;
  float* pre = (float*)p; p += 32768;
  float* neww= (float*)p; p += 32768;
  float* wf  = (float*)p; p += 32768;
  float* Yf  = (float*)p; p += 32768;
  int*   idxb= (int*)p;   p += 32768;
  int*   dofl= (int*)p;   p += 128;
  float* qf  = (float*)p; p += 64;
  float* ldb = (float*)p; p += 64;

  k_prep_xw0<<<256, 256, 0, stream>>>(x, Wih0, b0, xW0);
  k_init    <<<8192, 256, 0, stream>>>(part, h0A, h1A, c0, c1);

  float* h0in = h0A; float* h0out = h0B; float* h1in = h1A; float* h1out = h1B;
  for (int t = 0; t < TTN; ++t) {
    int last = (t == TTN-1);
    k_step_simple<<<512, 256, 0, stream>>>(h0in, (const float*)nullptr, Whh0, (const float*)nullptr,
        xW0, b1, c0, h0out, 0, t, last, pr, eps_h, eps_c, qp, ep);
    k_step_simple<<<512, 256, 0, stream>>>(h0out, h1in, Wih1, Whh1,
        xW0, b1, c1, h1out, 1, t, last, pr, eps_h, eps_c, qp, ep);
    float* tmp = h0in; h0in = h0out; h0out = tmp;
    tmp = h1in; h1in = h1out; h1out = tmp;
  }

  k_obs       <<<dim3(16,2), 256, 0, stream>>>(pr, Wh, bh, Yb);
  k_stats1    <<<16, 256, 0, stream>>>(Yb, wts, yv, rp, pre);
  k_colsoftmax<<<2, 256, 0, stream>>>(pre, neww);
  k_resample  <<<32, 256, 0, stream>>>(neww, gum, wf, idxb, dofl, out);
  k_pfg       <<<8192, 256, 0, stream>>>(pr, idxb, dofl, out);
  k_yf        <<<16, 512, 0, stream>>>(Yb, idxb, dofl, Yf);
  k_final_est <<<16, 256, 0, stream>>>(Yf, wf, yv, rp, qf, ldb, out);
  k_final_scalar<<<1, 64, 0, stream>>>(qf, ldb, out);
}

// Round 5
// 744.265 us; speedup vs baseline: 15.5586x; 15.5586x over previous
//
#include <hip/hip_runtime.h>
#include <hip/hip_bf16.h>
#include <math.h>

#define LSN 2
#define BSN 16
#define NH 256
#define NP 512
#define MIDP 256
#define TTN 16
#define DIN 64
#define NCH 4096
#define GW 1024

typedef _Float16 f16;
typedef _Float16 f16x8 __attribute__((ext_vector_type(8)));
typedef float f32x4 __attribute__((ext_vector_type(4)));

__device__ __forceinline__ float sigmoidf_(float x){ return 1.0f/(1.0f+expf(-x)); }

__device__ __forceinline__ float brsum(float v, float* red){
  int tid = threadIdx.x;
  red[tid]=v; __syncthreads();
  for (int s=128; s>0; s>>=1){ if (tid<s) red[tid]+=red[tid+s]; __syncthreads(); }
  float r = red[0]; __syncthreads(); return r;
}

// ---------- prep kernels ----------
// W0i[j'][k] = Whh0[(j'&3)*256 + (j'>>2)][k], fp16  (gate-interleaved rows)
__global__ void k_prep_w0(const float* __restrict__ Whh0, f16* __restrict__ W0i){
  int jp = blockIdx.x; int srow = (jp & 3)*NH + (jp >> 2);
  W0i[(size_t)jp*NH + threadIdx.x] = (f16)Whh0[(size_t)srow*NH + threadIdx.x];
}
// W1c[j'][k], k<256 from Wih1, k>=256 from Whh1
__global__ void k_prep_w1(const float* __restrict__ Wih1, const float* __restrict__ Whh1, f16* __restrict__ W1c){
  int jp = blockIdx.x; int srow = (jp & 3)*NH + (jp >> 2);
  for (int p=0;p<2;++p){
    int k = p*256 + threadIdx.x;
    float v = (k < 256) ? Wih1[(size_t)srow*NH + k] : Whh1[(size_t)srow*NH + (k-256)];
    W1c[(size_t)jp*512 + k] = (f16)v;
  }
}
__global__ void k_prep_b1(const float* __restrict__ b1, float* __restrict__ b1i){
  int jp = blockIdx.x*256 + threadIdx.x;
  b1i[jp] = b1[(jp & 3)*NH + (jp >> 2)];
}
// xW0[b*16+t][j'] interleaved: j' = n*4+q
__global__ void k_prep_xw0(const float* __restrict__ x, const float* __restrict__ Wih0,
                           const float* __restrict__ b0, float* __restrict__ xW0){
  int row = blockIdx.x; // b*16+t
  __shared__ float xr[DIN];
  if (threadIdx.x < DIN) xr[threadIdx.x] = x[(size_t)row*DIN + threadIdx.x];
  __syncthreads();
  int n = threadIdx.x;
  for (int q=0;q<4;++q){
    int wrow = q*NH + n;
    float acc = b0[wrow];
    #pragma unroll 8
    for (int d=0; d<DIN; ++d) acc += xr[d] * Wih0[(size_t)wrow*DIN + d];
    xW0[(size_t)row*GW + n*4 + q] = acc;
  }
}
// unpack particles -> h (fp16), c (f32); chain = i*16 + b
__global__ void k_init(const float* __restrict__ part, f16* h0, f16* h1, float* c0, float* c1){
  int row = blockIdx.x; // l*4096 + b*256 + n
  int i = threadIdx.x;
  int l = row >> 12, b = (row >> 8) & 15, n = row & 255;
  float hv = part[(size_t)row*NP + i];
  float cv = part[(size_t)row*NP + MIDP + i];
  int chain = i*BSN + b;
  if (l==0){ h0[(size_t)chain*NH+n]=(f16)hv; c0[(size_t)chain*NH+n]=cv; }
  else     { h1[(size_t)chain*NH+n]=(f16)hv; c1[(size_t)chain*NH+n]=cv; }
}

// ---------- fused LSTM step: 128x128 MFMA tile + gate epilogue ----------
__global__ __launch_bounds__(256) void k_lstm_step(
    const f16* __restrict__ A1, const f16* __restrict__ A2,
    const f16* __restrict__ W, int Kt, int nslice,
    const float* __restrict__ xw0, const float* __restrict__ b1i,
    float* __restrict__ C, f16* __restrict__ Hout,
    int layer, int t, int is_last,
    float* __restrict__ pr, const float* __restrict__ eps_h, const float* __restrict__ eps_c,
    const float* __restrict__ qp, const float* __restrict__ ep)
{
  __shared__ __align__(16) char smem[65536];
  f16* Asm = (f16*)smem;               // [128][72]
  f16* Bsm = Asm + 128*72;             // [128][72]
  float* Gs = (float*)smem;            // [128][128] (epilogue reuse)

  const int tid = threadIdx.x;
  const int lane = tid & 63, wid = tid >> 6;
  const int wm = (wid >> 1) * 64, wn = (wid & 1) * 64;
  const int m0 = blockIdx.x * 128, n0 = blockIdx.y * 128;

  f32x4 acc[4][4];
  #pragma unroll
  for (int i=0;i<4;i++)
    #pragma unroll
    for(int j=0;j<4;j++) acc[i][j] = (f32x4){0.f,0.f,0.f,0.f};

  const int srow = tid >> 1, sseg = (tid & 1) * 32;

  for (int ks = 0; ks < nslice; ++ks) {
    __syncthreads();
    const f16* Ab; int ka;
    if (layer == 1 && ks >= 4) { Ab = A2; ka = (ks-4)*64; } else { Ab = A1; ka = ks*64; }
    {
      const float4* src = (const float4*)(Ab + (size_t)(m0+srow)*NH + ka + sseg);
      float4* dst = (float4*)(Asm + srow*72 + sseg);
      dst[0]=src[0]; dst[1]=src[1]; dst[2]=src[2]; dst[3]=src[3];
      const float4* srcB = (const float4*)(W + (size_t)(n0+srow)*Kt + ks*64 + sseg);
      float4* dstB = (float4*)(Bsm + srow*72 + sseg);
      dstB[0]=srcB[0]; dstB[1]=srcB[1]; dstB[2]=srcB[2]; dstB[3]=srcB[3];
    }
    __syncthreads();
    #pragma unroll
    for (int k2 = 0; k2 < 2; ++k2) {
      const int koff = k2*32 + ((lane>>4)<<3);
      f16x8 a[4], b[4];
      #pragma unroll
      for (int mi=0; mi<4; ++mi)
        a[mi] = *(const f16x8*)(Asm + (wm + mi*16 + (lane&15))*72 + koff);
      #pragma unroll
      for (int ni=0; ni<4; ++ni)
        b[ni] = *(const f16x8*)(Bsm + (wn + ni*16 + (lane&15))*72 + koff);
      #pragma unroll
      for (int mi=0; mi<4; ++mi)
        #pragma unroll
        for (int ni=0; ni<4; ++ni)
          acc[mi][ni] = __builtin_amdgcn_mfma_f32_16x16x32_f16(a[mi], b[ni], acc[mi][ni], 0, 0, 0);
    }
  }
  __syncthreads();
  #pragma unroll
  for (int mi=0;mi<4;++mi)
    #pragma unroll
    for (int ni=0;ni<4;++ni)
      #pragma unroll
      for (int r=0;r<4;++r) {
        int ml = wm + mi*16 + ((lane>>4)<<2) + r;
        int nl = wn + ni*16 + (lane&15);
        Gs[ml*128 + nl] = acc[mi][ni][r];
      }
  __syncthreads();

  float sq=0.f, se=0.f;
  if (is_last) { sq = sqrtf(qp[0]*qp[0]); se = sqrtf(ep[0]*ep[0]); }

  for (int rep = 0; rep < 16; ++rep) {
    int u = rep*256 + tid;
    int cl = u >> 5, nl = u & 31;
    float4 g4 = *(const float4*)(Gs + cl*128 + nl*4);
    int chain = m0 + cl;
    int bb = chain & 15;
    int nglob = (n0 >> 2) + nl;
    float4 add;
    if (layer == 0) add = *(const float4*)(xw0 + (size_t)((bb<<4)+t)*GW + n0 + nl*4);
    else            add = *(const float4*)(b1i + n0 + nl*4);
    float gi = g4.x + add.x, gf = g4.y + add.y, gg = g4.z + add.z, go = g4.w + add.w;
    float cold = C[(size_t)chain*NH + nglob];
    float c2 = sigmoidf_(gf)*cold + sigmoidf_(gi)*tanhf(gg);
    float h2 = sigmoidf_(go)*tanhf(c2);
    Hout[(size_t)chain*NH + nglob] = (f16)h2;
    if (!is_last) {
      C[(size_t)chain*NH + nglob] = c2;
    } else {
      int ip = chain >> 4;
      size_t rowp = (size_t)(layer*BSN + bb)*NH + nglob;
      size_t eidx = ((size_t)(ip*LSN + layer)*BSN + bb)*NH + nglob;
      pr[rowp*NP + ip]         = h2 + sq * eps_h[eidx];
      pr[rowp*NP + MIDP + ip]  = c2 + se * eps_c[eidx];
    }
  }
}

// ---------- post kernels ----------
__global__ void k_obs(const float* __restrict__ pr, const float* __restrict__ Wh,
                      const float* __restrict__ bh, float* __restrict__ Y){
  int b = blockIdx.x; int N = blockIdx.y*256 + threadIdx.x;
  float acc = bh[0];
  for (int n=0;n<NH;++n) acc += Wh[n] * pr[((size_t)(BSN + b)*NH + n)*NP + N];
  Y[(size_t)b*NP + N] = acc;
}

__global__ void k_stats1(const float* __restrict__ Y, const float* __restrict__ wts,
                         const float* __restrict__ yv, const float* __restrict__ rp,
                         float* __restrict__ pre){
  int b = blockIdx.x, tid = threadIdx.x;
  __shared__ float red[256];
  float lw0 = logf(wts[b*NP+tid]),     lw1 = logf(wts[b*NP+256+tid]);
  float y0  = Y[b*NP+tid],             y1  = Y[b*NP+256+tid];
  float SW = brsum(lw0+lw1, red);
  float SY = brsum(y0*lw0 + y1*lw1, red);
  float mu = SY/SW;
  float c0=y0-mu, c1=y1-mu;
  float SC = brsum(c0*c0+c1*c1, red);
  float sig = SC/511.0f + rp[0]*rp[0];
  float a = sig+1e-6f, inv = 1.0f/a, ld = logf(a);
  float yb = yv[b];
  float i0 = yb - y0*lw0/SW;
  float i1 = yb - y1*lw1/SW;
  pre[b*NP+tid]     = lw0 - 0.5f*ld - 0.5f*inv*i0*i0;
  pre[b*NP+256+tid] = lw1 - 0.5f*ld - 0.5f*inv*i1*i1;
}

__global__ void k_colsoftmax(const float* __restrict__ pre, float* __restrict__ neww){
  int N = blockIdx.x*256 + threadIdx.x;
  float s=0.f;
  for(int b=0;b<BSN;b++) s += expf(pre[b*NP+N]);
  float ls = logf(s);
  for(int b=0;b<BSN;b++) neww[b*NP+N] = expf(pre[b*NP+N] - ls);
}

__global__ void k_resample(const float* __restrict__ neww, const float* __restrict__ gum,
                           float* __restrict__ wf, int* __restrict__ idxb, int* __restrict__ dofl,
                           float* __restrict__ out){
  int b = blockIdx.x >> 1, hf = blockIdx.x & 1, j = threadIdx.x;
  __shared__ float red[256]; __shared__ float key[256];
  float wh = neww[b*NP + hf*256 + j];
  red[j] = wh*wh; __syncthreads();
  for (int s=128;s>0;s>>=1){ if(j<s) red[j]+=red[j+s]; __syncthreads(); }
  float s2 = red[0]; __syncthreads();
  int doit = (1.0f/s2) < (float)(NP)/4.0f;
  float soft = 0.5f*wh + (0.5f/(float)MIDP);
  float kk = logf(soft) + gum[(b*2+hf)*256 + j];
  key[j] = kk; __syncthreads();
  int rank = 0;
  for (int m=0;m<256;++m){ float km = key[m]; rank += (km > kk) || (km == kk && m < j); }
  idxb[(b*2+hf)*256 + rank] = j;
  float lw = logf(wh/soft);
  red[j] = lw; __syncthreads();
  for (int s=128;s>0;s>>=1){ if(j<s) red[j] = fmaxf(red[j],red[j+s]); __syncthreads(); }
  float mx = red[0]; __syncthreads();
  red[j] = expf(lw-mx); __syncthreads();
  for (int s=128;s>0;s>>=1){ if(j<s) red[j]+=red[j+s]; __syncthreads(); }
  float lse = mx + logf(red[0]);
  float wr = expf(lw - lse);
  float wv = doit ? wr : wh;
  wf[b*NP + hf*256 + j] = wv;
  out[4194336 + b*NP + hf*256 + j] = wv;
  if (j==0) dofl[b*2+hf] = doit;
}

__global__ void k_pfg(const float* __restrict__ pr, const int* __restrict__ idxb,
                      const int* __restrict__ dofl, float* __restrict__ out){
  size_t row = blockIdx.x; // l*4096 + b*256 + n
  int b = (blockIdx.x >> 8) & 15;
  const float* src = pr + row*NP;
  for (int hf=0; hf<2; ++hf){
    int loc = threadIdx.x;
    int N = hf*256 + loc;
    int dcol = dofl[b*2+hf] ? hf*256 + idxb[(b*2+hf)*256 + loc] : N;
    out[32 + row*NP + N] = src[dcol];
  }
}

__global__ void k_yf(const float* __restrict__ Y, const int* __restrict__ idxb,
                     const int* __restrict__ dofl, float* __restrict__ Yf){
  int b = blockIdx.x; int N = threadIdx.x; int hf = N >> 8; int loc = N & 255;
  int dcol = dofl[b*2+hf] ? hf*256 + idxb[(b*2+hf)*256 + loc] : N;
  Yf[b*NP+N] = Y[b*NP+dcol];
}

__global__ void k_final_est(const float* __restrict__ Yf, const float* __restrict__ wf,
                            const float* __restrict__ yv, const float* __restrict__ rp,
                            float* __restrict__ qf, float* __restrict__ ldb,
                            float* __restrict__ out){
  int b = blockIdx.x, tid = threadIdx.x;
  __shared__ float red[256];
  float w0 = wf[b*NP+tid], w1 = wf[b*NP+256+tid];
  float y0 = Yf[b*NP+tid], y1 = Yf[b*NP+256+tid];
  float SW = brsum(w0+w1, red);
  float SY = brsum(y0*w0+y1*w1, red);
  float mu = SY/SW;
  float c0=y0-mu, c1=y1-mu;
  float SC = brsum(c0*c0+c1*c1, red);
  float sig = SC/511.0f + rp[0]*rp[0];
  if (tid==0){
    float a = sig + 1e-6f; float inv = 1.0f/a; float ld = logf(a);
    float inn = yv[b]-mu; float q = inn*inn*inv;
    qf[b]=q; ldb[b]=ld;
    out[b]      = mu;
    out[16 + b] = sig;
  }
}

__global__ void k_final_scalar(const float* __restrict__ qf, const float* __restrict__ ldb,
                               float* __restrict__ out){
  if (threadIdx.x==0){
    float l=0.f, nq=0.f;
    for(int b=0;b<BSN;b++){ l += -0.5f*ldb[b]-0.5f*qf[b]; nq += qf[b]; }
    out[4202528] = l;
    out[4202529] = nq/16.0f;
  }
}

extern "C" void kernel_launch(void* const* d_in, const int* in_sizes, int n_in,
                              void* d_out, int out_size, void* d_ws, size_t ws_size,
                              hipStream_t stream) {
  const float* x      = (const float*)d_in[0];
  const float* yv     = (const float*)d_in[1];
  const float* part   = (const float*)d_in[2];
  const float* wts    = (const float*)d_in[3];
  const float* qp     = (const float*)d_in[4];
  const float* ep     = (const float*)d_in[5];
  const float* rp     = (const float*)d_in[6];
  const float* Wih0   = (const float*)d_in[7];
  const float* Whh0   = (const float*)d_in[8];
  const float* b0     = (const float*)d_in[9];
  const float* Wih1   = (const float*)d_in[10];
  const float* Whh1   = (const float*)d_in[11];
  const float* b1     = (const float*)d_in[12];
  const float* Wh     = (const float*)d_in[13];
  const float* bh     = (const float*)d_in[14];
  const float* eps_h  = (const float*)d_in[15];
  const float* eps_c  = (const float*)d_in[16];
  const float* gum    = (const float*)d_in[17];
  float* out = (float*)d_out;

  char* p = (char*)d_ws;
  f16*   W0i  = (f16*)p;  p += (size_t)GW*NH*2;        // 512 KB
  f16*   W1c  = (f16*)p;  p += (size_t)GW*512*2;       // 1 MB
  float* b1i  = (float*)p; p += (size_t)GW*4;          // 4 KB
  float* xW0  = (float*)p; p += (size_t)256*GW*4;      // 1 MB
  f16*   h0A  = (f16*)p;  p += (size_t)NCH*NH*2;       // 2 MB
  f16*   h0B  = (f16*)p;  p += (size_t)NCH*NH*2;
  f16*   h1A  = (f16*)p;  p += (size_t)NCH*NH*2;
  f16*   h1B  = (f16*)p;  p += (size_t)NCH*NH*2;
  float* c0   = (float*)p; p += (size_t)NCH*NH*4;      // 4 MB
  float* c1   = (float*)p; p += (size_t)NCH*NH*4;
  float* pr   = (float*)p; p += (size_t)LSN*BSN*NH*NP*4; // 16 MB
  float* Yb   = (float*)p; p += 32768;
  float* pre  = (float*)p; p += 32768;
  float* neww = (float*)p; p += 32768;
  float* wf   = (float*)p; p += 32768;
  float* Yf   = (float*)p; p += 32768;
  int*   idxb = (int*)p;   p += 32768;
  int*   dofl = (int*)p;   p += 128;
  float* qf   = (float*)p; p += 64;
  float* ldb  = (float*)p; p += 64;

  k_prep_w0 <<<1024, 256, 0, stream>>>(Whh0, W0i);
  k_prep_w1 <<<1024, 256, 0, stream>>>(Wih1, Whh1, W1c);
  k_prep_b1 <<<4, 256, 0, stream>>>(b1, b1i);
  k_prep_xw0<<<256, 256, 0, stream>>>(x, Wih0, b0, xW0);
  k_init    <<<8192, 256, 0, stream>>>(part, h0A, h1A, c0, c1);

  f16* h0in = h0A; f16* h0out = h0B; f16* h1in = h1A; f16* h1out = h1B;
  for (int t = 0; t < TTN; ++t) {
    int last = (t == TTN-1);
    k_lstm_step<<<dim3(32,8), 256, 0, stream>>>(h0in, (const f16*)nullptr, W0i, 256, 4,
        xW0, b1i, c0, h0out, 0, t, last, pr, eps_h, eps_c, qp, ep);
    k_lstm_step<<<dim3(32,8), 256, 0, stream>>>(h0out, h1in, W1c, 512, 8,
        xW0, b1i, c1, h1out, 1, t, last, pr, eps_h, eps_c, qp, ep);
    f16* tmp = h0in; h0in = h0out; h0out = tmp;
    tmp = h1in; h1in = h1out; h1out = tmp;
  }

  k_obs       <<<dim3(16,2), 256, 0, stream>>>(pr, Wh, bh, Yb);
  k_stats1    <<<16, 256, 0, stream>>>(Yb, wts, yv, rp, pre);
  k_colsoftmax<<<2, 256, 0, stream>>>(pre, neww);
  k_resample  <<<32, 256, 0, stream>>>(neww, gum, wf, idxb, dofl, out);
  k_pfg       <<<8192, 256, 0, stream>>>(pr, idxb, dofl, out);
  k_yf        <<<16, 512, 0, stream>>>(Yb, idxb, dofl, Yf);
  k_final_est <<<16, 256, 0, stream>>>(Yf, wf, yv, rp, qf, ldb, out);
  k_final_scalar<<<1, 64, 0, stream>>>(qf, ldb, out);
}

// Round 9
// 432.641 us; speedup vs baseline: 26.7652x; 1.7203x over previous
//
#include <hip/hip_runtime.h>
#include <hip/hip_bf16.h>
#include <math.h>

#define LSN 2
#define BSN 16
#define NH 256
#define NP 512
#define MIDP 256
#define TTN 16
#define DIN 64
#define NCH 4096
#define GW 1024
#define PRS 268   // prstage LDS row stride (floats)

typedef _Float16 f16;
typedef _Float16 f16x8 __attribute__((ext_vector_type(8)));
typedef float f32x4 __attribute__((ext_vector_type(4)));

// r5-proven activation numerics (libm expf/tanhf). DO NOT replace with __expf:
// fp16-amplified activation noise flips resample argsort near-ties (r6-r8).
__device__ __forceinline__ float fsig(float x){ return 1.0f/(1.0f+expf(-x)); }

__device__ __forceinline__ float brsum(float v, float* red){
  int tid = threadIdx.x;
  red[tid]=v; __syncthreads();
  for (int s=128; s>0; s>>=1){ if (tid<s) red[tid]+=red[tid+s]; __syncthreads(); }
  float r = red[0]; __syncthreads(); return r;
}

// gate-row remap: jhat = y*128 + q*32 + m  <->  source row = q*256 + y*32 + m
__device__ __forceinline__ int gsrow(int jp){
  return ((jp>>5)&3)*NH + (jp>>7)*32 + (jp&31);
}

// ---------- prep kernels ----------
__global__ void k_prep_w0(const float* __restrict__ Whh0, f16* __restrict__ W0i){
  int jp = blockIdx.x; int srow = gsrow(jp);
  W0i[(size_t)jp*NH + threadIdx.x] = (f16)Whh0[(size_t)srow*NH + threadIdx.x];
}
__global__ void k_prep_w1(const float* __restrict__ Wih1, const float* __restrict__ Whh1, f16* __restrict__ W1c){
  int jp = blockIdx.x; int srow = gsrow(jp);
  for (int p=0;p<2;++p){
    int k = p*256 + threadIdx.x;
    float v = (k < 256) ? Wih1[(size_t)srow*NH + k] : Whh1[(size_t)srow*NH + (k-256)];
    W1c[(size_t)jp*512 + k] = (f16)v;
  }
}
__global__ void k_prep_b1(const float* __restrict__ b1, float* __restrict__ b1i){
  int jp = blockIdx.x*256 + threadIdx.x;
  b1i[jp] = b1[gsrow(jp)];
}
__global__ void k_prep_xw0(const float* __restrict__ x, const float* __restrict__ Wih0,
                           const float* __restrict__ b0, float* __restrict__ xW0){
  int row = blockIdx.x; // b*16+t
  __shared__ float xr[DIN];
  if (threadIdx.x < DIN) xr[threadIdx.x] = x[(size_t)row*DIN + threadIdx.x];
  __syncthreads();
  int n = threadIdx.x;
  for (int q=0;q<4;++q){
    int wrow = q*NH + n;
    float acc = b0[wrow];
    #pragma unroll 8
    for (int d=0; d<DIN; ++d) acc += xr[d] * Wih0[(size_t)wrow*DIN + d];
    int jhat = (n>>5)*128 + q*32 + (n&31);
    xW0[(size_t)row*GW + jhat] = acc;
  }
}

// unpack particles, chain = b*256 + i, via LDS transpose (coalesced both sides)
__global__ __launch_bounds__(256) void k_init(const float* __restrict__ part,
                f16* __restrict__ h0, f16* __restrict__ h1,
                float* __restrict__ c0, float* __restrict__ c1){
  __shared__ float lh[64][65];
  __shared__ float lcv[64][65];
  int l = blockIdx.z, b = blockIdx.y;
  int i0 = (blockIdx.x >> 2)*64, n0 = (blockIdx.x & 3)*64;
  int tid = threadIdx.x;
  #pragma unroll
  for (int rep=0; rep<16; ++rep){
    int nn = rep*4 + (tid>>6);
    int ii = tid & 63;
    size_t rowb = ((size_t)(l*BSN + b)*NH + n0 + nn)*NP;
    lh[nn][ii]  = part[rowb + i0 + ii];
    lcv[nn][ii] = part[rowb + MIDP + i0 + ii];
  }
  __syncthreads();
  f16* h = l ? h1 : h0;
  float* c = l ? c1 : c0;
  #pragma unroll
  for (int rep=0; rep<16; ++rep){
    int ii = rep*4 + (tid>>6);
    int nn = tid & 63;
    size_t chain = (size_t)b*256 + i0 + ii;
    h[chain*NH + n0 + nn] = (f16)lh[nn][ii];
    c[chain*NH + n0 + nn] = lcv[nn][ii];
  }
}

// ---------- fused step: z=0 -> cfgA, z=1 -> cfgB ----------
struct StepCfg {
  const f16* A1; const f16* A2;
  float* C; f16* Hout;
  int layer; int t; int is_last;
};

__global__ __launch_bounds__(256) void k_step2(
    StepCfg cfgA, StepCfg cfgB,
    const f16* __restrict__ W0i, const f16* __restrict__ W1c,
    const float* __restrict__ xw0, const float* __restrict__ b1i,
    float* __restrict__ pr, const float* __restrict__ eps_h, const float* __restrict__ eps_c,
    const float* __restrict__ qp, const float* __restrict__ ep)
{
  __shared__ __align__(16) char smem[36864];
  f16* Asm = (f16*)smem;          // [128][72]
  f16* Bsm = Asm + 128*72;        // [128][72]

  const StepCfg cfg = blockIdx.z ? cfgB : cfgA;
  const int layer  = cfg.layer;
  const int Kt     = layer ? 512 : 256;
  const int nslice = layer ? 8 : 4;
  const f16* W     = layer ? W1c : W0i;

  const int tid = threadIdx.x;
  const int lane = tid & 63, wid = tid >> 6;
  const int lr = lane >> 4, lc = lane & 15;
  const int wm = wid * 32;
  const int m0 = blockIdx.x * 128;
  const int y  = blockIdx.y;          // element cols nglob in [y*32, y*32+32)
  const int bb = blockIdx.x >> 1;     // chain = b*256+i  ->  b uniform per block

  // prefetch C state (16 regs, consumed in epilogue)
  float cold[2][2][4];
  #pragma unroll
  for (int mi=0; mi<2; ++mi)
    #pragma unroll
    for (int mh=0; mh<2; ++mh)
      #pragma unroll
      for (int r=0; r<4; ++r)
        cold[mi][mh][r] = cfg.C[(size_t)(m0 + wm + mi*16 + lr*4 + r)*NH + y*32 + mh*16 + lc];

  f32x4 acc[2][8];
  #pragma unroll
  for (int mi=0;mi<2;++mi)
    #pragma unroll
    for (int ni=0;ni<8;++ni) acc[mi][ni] = (f32x4){0.f,0.f,0.f,0.f};

  const int srow = tid >> 1, sseg = (tid & 1)*32;
  for (int ks=0; ks<nslice; ++ks){
    __syncthreads();
    const f16* Ab; int ka;
    if (layer==1 && ks>=4){ Ab = cfg.A2; ka = (ks-4)*64; } else { Ab = cfg.A1; ka = ks*64; }
    {
      const float4* src = (const float4*)(Ab + (size_t)(m0+srow)*NH + ka + sseg);
      float4* dst = (float4*)(Asm + srow*72 + sseg);
      dst[0]=src[0]; dst[1]=src[1]; dst[2]=src[2]; dst[3]=src[3];
      const float4* srcB = (const float4*)(W + (size_t)(y*128+srow)*Kt + ks*64 + sseg);
      float4* dstB = (float4*)(Bsm + srow*72 + sseg);
      dstB[0]=srcB[0]; dstB[1]=srcB[1]; dstB[2]=srcB[2]; dstB[3]=srcB[3];
    }
    __syncthreads();
    #pragma unroll
    for (int k2=0;k2<2;++k2){
      const int koff = k2*32 + lr*8;
      f16x8 a0 = *(const f16x8*)(Asm + (wm +  0 + lc)*72 + koff);
      f16x8 a1 = *(const f16x8*)(Asm + (wm + 16 + lc)*72 + koff);
      f16x8 b[8];
      #pragma unroll
      for (int ni=0;ni<8;++ni) b[ni] = *(const f16x8*)(Bsm + (ni*16 + lc)*72 + koff);
      #pragma unroll
      for (int ni=0;ni<8;++ni){
        acc[0][ni] = __builtin_amdgcn_mfma_f32_16x16x32_f16(a0, b[ni], acc[0][ni], 0,0,0);
        acc[1][ni] = __builtin_amdgcn_mfma_f32_16x16x32_f16(a1, b[ni], acc[1][ni], 0,0,0);
      }
    }
  }

  // per-element adds: all 4 gates of one element live in this lane (ni = 2q+mh)
  float addv[4][2];
  {
    const float* ar = (layer==0) ? (xw0 + (size_t)(bb*TTN + cfg.t)*GW + y*128)
                                 : (b1i + y*128);
    #pragma unroll
    for (int q=0;q<4;++q)
      #pragma unroll
      for (int mh=0;mh<2;++mh)
        addv[q][mh] = ar[q*32 + mh*16 + lc];
  }

  float sq=0.f, se=0.f;
  float* prstage = (float*)smem;   // [32][PRS] overlay (reused after MFMA)
  if (cfg.is_last){
    sq = sqrtf(qp[0]*qp[0]); se = sqrtf(ep[0]*ep[0]);
    __syncthreads();   // all warps done reading Asm/Bsm before overlay
  }

  #pragma unroll
  for (int mi=0;mi<2;++mi)
   #pragma unroll
   for (int mh=0;mh<2;++mh)
    #pragma unroll
    for (int r=0;r<4;++r){
      float gi = acc[mi][mh+0][r] + addv[0][mh];
      float gf = acc[mi][mh+2][r] + addv[1][mh];
      float gg = acc[mi][mh+4][r] + addv[2][mh];
      float go = acc[mi][mh+6][r] + addv[3][mh];
      float c2 = fsig(gf)*cold[mi][mh][r] + fsig(gi)*tanhf(gg);
      float h2 = fsig(go)*tanhf(c2);
      int ml = wm + mi*16 + lr*4 + r;
      int chain = m0 + ml;
      int nglob = y*32 + mh*16 + lc;
      cfg.Hout[(size_t)chain*NH + nglob] = (f16)h2;
      if (!cfg.is_last){
        cfg.C[(size_t)chain*NH + nglob] = c2;
      } else {
        int ip = (blockIdx.x & 1)*128 + ml;
        size_t eidx = ((size_t)(ip*LSN + layer)*BSN + bb)*NH + nglob;
        int nl = mh*16 + lc;
        prstage[nl*PRS + ml]       = h2 + sq*eps_h[eidx];
        prstage[nl*PRS + 128 + ml] = c2 + se*eps_c[eidx];
      }
    }

  if (cfg.is_last){
    __syncthreads();
    #pragma unroll
    for (int s=0;s<8;++s){
      int u = s*256 + tid;
      int nl = u >> 6, within = u & 63;
      int half = within >> 5, q4 = within & 31;
      size_t rowp = (size_t)(layer*BSN + bb)*NH + y*32 + nl;
      float4 v = *(const float4*)(prstage + nl*PRS + half*128 + q4*4);
      *(float4*)(pr + rowp*NP + half*MIDP + (blockIdx.x & 1)*128 + q4*4) = v;
    }
  }
}

// ---------- post kernels ----------
__global__ void k_obs(const float* __restrict__ pr, const float* __restrict__ Wh,
                      const float* __restrict__ bh, float* __restrict__ Y){
  int b = blockIdx.x; int N = blockIdx.y*256 + threadIdx.x;
  float acc = bh[0];
  for (int n=0;n<NH;++n) acc += Wh[n] * pr[((size_t)(BSN + b)*NH + n)*NP + N];
  Y[(size_t)b*NP + N] = acc;
}

__global__ void k_stats1(const float* __restrict__ Y, const float* __restrict__ wts,
                         const float* __restrict__ yv, const float* __restrict__ rp,
                         float* __restrict__ pre){
  int b = blockIdx.x, tid = threadIdx.x;
  __shared__ float red[256];
  float lw0 = logf(wts[b*NP+tid]),     lw1 = logf(wts[b*NP+256+tid]);
  float y0  = Y[b*NP+tid],             y1  = Y[b*NP+256+tid];
  float SW = brsum(lw0+lw1, red);
  float SY = brsum(y0*lw0 + y1*lw1, red);
  float mu = SY/SW;
  float c0=y0-mu, c1=y1-mu;
  float SC = brsum(c0*c0+c1*c1, red);
  float sig = SC/511.0f + rp[0]*rp[0];
  float a = sig+1e-6f, inv = 1.0f/a, ld = logf(a);
  float yb = yv[b];
  float i0 = yb - y0*lw0/SW;
  float i1 = yb - y1*lw1/SW;
  pre[b*NP+tid]     = lw0 - 0.5f*ld - 0.5f*inv*i0*i0;
  pre[b*NP+256+tid] = lw1 - 0.5f*ld - 0.5f*inv*i1*i1;
}

__global__ void k_colsoftmax(const float* __restrict__ pre, float* __restrict__ neww){
  int N = blockIdx.x*256 + threadIdx.x;
  float s=0.f;
  for(int b=0;b<BSN;b++) s += expf(pre[b*NP+N]);
  float ls = logf(s);
  for(int b=0;b<BSN;b++) neww[b*NP+N] = expf(pre[b*NP+N] - ls);
}

__global__ void k_resample(const float* __restrict__ neww, const float* __restrict__ gum,
                           float* __restrict__ wf, int* __restrict__ idxb, int* __restrict__ dofl,
                           float* __restrict__ out){
  int b = blockIdx.x >> 1, hf = blockIdx.x & 1, j = threadIdx.x;
  __shared__ float red[256]; __shared__ float key[256];
  float wh = neww[b*NP + hf*256 + j];
  red[j] = wh*wh; __syncthreads();
  for (int s=128;s>0;s>>=1){ if(j<s) red[j]+=red[j+s]; __syncthreads(); }
  float s2 = red[0]; __syncthreads();
  int doit = (1.0f/s2) < (float)(NP)/4.0f;
  float soft = 0.5f*wh + (0.5f/(float)MIDP);
  float kk = logf(soft) + gum[(b*2+hf)*256 + j];
  key[j] = kk; __syncthreads();
  int rank = 0;
  for (int m=0;m<256;++m){ float km = key[m]; rank += (km > kk) || (km == kk && m < j); }
  idxb[(b*2+hf)*256 + rank] = j;
  float lw = logf(wh/soft);
  red[j] = lw; __syncthreads();
  for (int s=128;s>0;s>>=1){ if(j<s) red[j] = fmaxf(red[j],red[j+s]); __syncthreads(); }
  float mx = red[0]; __syncthreads();
  red[j] = expf(lw-mx); __syncthreads();
  for (int s=128;s>0;s>>=1){ if(j<s) red[j]+=red[j+s]; __syncthreads(); }
  float lse = mx + logf(red[0]);
  float wr = expf(lw - lse);
  float wv = doit ? wr : wh;
  wf[b*NP + hf*256 + j] = wv;
  out[4194336 + b*NP + hf*256 + j] = wv;
  if (j==0) dofl[b*2+hf] = doit;
}

__global__ void k_pfg(const float* __restrict__ pr, const int* __restrict__ idxb,
                      const int* __restrict__ dofl, float* __restrict__ out){
  size_t row = blockIdx.x; // l*4096 + b*256 + n
  int b = (blockIdx.x >> 8) & 15;
  const float* src = pr + row*NP;
  for (int hf=0; hf<2; ++hf){
    int loc = threadIdx.x;
    int N = hf*256 + loc;
    int dcol = dofl[b*2+hf] ? hf*256 + idxb[(b*2+hf)*256 + loc] : N;
    out[32 + row*NP + N] = src[dcol];
  }
}

__global__ void k_yf(const float* __restrict__ Y, const int* __restrict__ idxb,
                     const int* __restrict__ dofl, float* __restrict__ Yf){
  int b = blockIdx.x; int N = threadIdx.x; int hf = N >> 8; int loc = N & 255;
  int dcol = dofl[b*2+hf] ? hf*256 + idxb[(b*2+hf)*256 + loc] : N;
  Yf[b*NP+N] = Y[b*NP+dcol];
}

__global__ void k_final_est(const float* __restrict__ Yf, const float* __restrict__ wf,
                            const float* __restrict__ yv, const float* __restrict__ rp,
                            float* __restrict__ qf, float* __restrict__ ldb,
                            float* __restrict__ out){
  int b = blockIdx.x, tid = threadIdx.x;
  __shared__ float red[256];
  float w0 = wf[b*NP+tid], w1 = wf[b*NP+256+tid];
  float y0 = Yf[b*NP+tid], y1 = Yf[b*NP+256+tid];
  float SW = brsum(w0+w1, red);
  float SY = brsum(y0*w0+y1*w1, red);
  float mu = SY/SW;
  float c0=y0-mu, c1=y1-mu;
  float SC = brsum(c0*c0+c1*c1, red);
  float sig = SC/511.0f + rp[0]*rp[0];
  if (tid==0){
    float a = sig + 1e-6f; float inv = 1.0f/a; float ld = logf(a);
    float inn = yv[b]-mu; float q = inn*inn*inv;
    qf[b]=q; ldb[b]=ld;
    out[b]      = mu;
    out[16 + b] = sig;
  }
}

__global__ void k_final_scalar(const float* __restrict__ qf, const float* __restrict__ ldb,
                               float* __restrict__ out){
  if (threadIdx.x==0){
    float l=0.f, nq=0.f;
    for(int b=0;b<BSN;b++){ l += -0.5f*ldb[b]-0.5f*qf[b]; nq += qf[b]; }
    out[4202528] = l;
    out[4202529] = nq/16.0f;
  }
}

extern "C" void kernel_launch(void* const* d_in, const int* in_sizes, int n_in,
                              void* d_out, int out_size, void* d_ws, size_t ws_size,
                              hipStream_t stream) {
  const float* x      = (const float*)d_in[0];
  const float* yv     = (const float*)d_in[1];
  const float* part   = (const float*)d_in[2];
  const float* wts    = (const float*)d_in[3];
  const float* qp     = (const float*)d_in[4];
  const float* ep     = (const float*)d_in[5];
  const float* rp     = (const float*)d_in[6];
  const float* Wih0   = (const float*)d_in[7];
  const float* Whh0   = (const float*)d_in[8];
  const float* b0     = (const float*)d_in[9];
  const float* Wih1   = (const float*)d_in[10];
  const float* Whh1   = (const float*)d_in[11];
  const float* b1     = (const float*)d_in[12];
  const float* Wh     = (const float*)d_in[13];
  const float* bh     = (const float*)d_in[14];
  const float* eps_h  = (const float*)d_in[15];
  const float* eps_c  = (const float*)d_in[16];
  const float* gum    = (const float*)d_in[17];
  float* out = (float*)d_out;

  char* p = (char*)d_ws;
  f16*   W0i  = (f16*)p;  p += (size_t)GW*NH*2;
  f16*   W1c  = (f16*)p;  p += (size_t)GW*512*2;
  float* b1i  = (float*)p; p += (size_t)GW*4;
  float* xW0  = (float*)p; p += (size_t)256*GW*4;
  f16*   h0A  = (f16*)p;  p += (size_t)NCH*NH*2;
  f16*   h0B  = (f16*)p;  p += (size_t)NCH*NH*2;
  f16*   h1A  = (f16*)p;  p += (size_t)NCH*NH*2;
  f16*   h1B  = (f16*)p;  p += (size_t)NCH*NH*2;
  float* c0   = (float*)p; p += (size_t)NCH*NH*4;
  float* c1   = (float*)p; p += (size_t)NCH*NH*4;
  float* pr   = (float*)p; p += (size_t)LSN*BSN*NH*NP*4;
  float* Yb   = (float*)p; p += 32768;
  float* pre  = (float*)p; p += 32768;
  float* neww = (float*)p; p += 32768;
  float* wf   = (float*)p; p += 32768;
  float* Yf   = (float*)p; p += 32768;
  int*   idxb = (int*)p;   p += 32768;
  int*   dofl = (int*)p;   p += 128;
  float* qf   = (float*)p; p += 64;
  float* ldb  = (float*)p; p += 64;

  k_prep_w0 <<<1024, 256, 0, stream>>>(Whh0, W0i);
  k_prep_w1 <<<1024, 256, 0, stream>>>(Wih1, Whh1, W1c);
  k_prep_b1 <<<4, 256, 0, stream>>>(b1, b1i);
  k_prep_xw0<<<256, 256, 0, stream>>>(x, Wih0, b0, xW0);
  k_init    <<<dim3(16,16,2), 256, 0, stream>>>(part, h0A, h1A, c0, c1);

  // step 0, layer 0 only
  {
    StepCfg s0{h0A, nullptr, c0, h0B, 0, 0, 0};
    k_step2<<<dim3(32,8,1), 256, 0, stream>>>(s0, s0, W0i, W1c, xW0, b1i,
        pr, eps_h, eps_c, qp, ep);
  }
  f16 *h0cur=h0B, *h0nxt=h0A, *h1cur=h1A, *h1nxt=h1B;
  for (int t=0; t<15; ++t){
    StepCfg ca{h0cur, nullptr, c0, h0nxt, 0, t+1, (t+1==15) ? 1 : 0}; // layer0 step t+1
    StepCfg cb{h0cur, h1cur,   c1, h1nxt, 1, t,   0};                 // layer1 step t
    k_step2<<<dim3(32,8,2), 256, 0, stream>>>(ca, cb, W0i, W1c, xW0, b1i,
        pr, eps_h, eps_c, qp, ep);
    f16* tmp = h0cur; h0cur = h0nxt; h0nxt = tmp;
    tmp = h1cur; h1cur = h1nxt; h1nxt = tmp;
  }
  // final: layer 1, t=15
  {
    StepCfg fin{h0cur, h1cur, c1, h1nxt, 1, 15, 1};
    k_step2<<<dim3(32,8,1), 256, 0, stream>>>(fin, fin, W0i, W1c, xW0, b1i,
        pr, eps_h, eps_c, qp, ep);
  }

  k_obs       <<<dim3(16,2), 256, 0, stream>>>(pr, Wh, bh, Yb);
  k_stats1    <<<16, 256, 0, stream>>>(Yb, wts, yv, rp, pre);
  k_colsoftmax<<<2, 256, 0, stream>>>(pre, neww);
  k_resample  <<<32, 256, 0, stream>>>(neww, gum, wf, idxb, dofl, out);
  k_pfg       <<<8192, 256, 0, stream>>>(pr, idxb, dofl, out);
  k_yf        <<<16, 512, 0, stream>>>(Yb, idxb, dofl, Yf);
  k_final_est <<<16, 256, 0, stream>>>(Yf, wf, yv, rp, qf, ldb, out);
  k_final_scalar<<<1, 64, 0, stream>>>(qf, ldb, out);
}

// Round 10
// 400.659 us; speedup vs baseline: 28.9016x; 1.0798x over previous
//
#include <hip/hip_runtime.h>
#include <hip/hip_bf16.h>
#include <math.h>

#define LSN 2
#define BSN 16
#define NH 256
#define NP 512
#define MIDP 256
#define TTN 16
#define DIN 64
#define NCH 4096
#define GW 1024
#define PRS 268   // prstage LDS row stride (floats)
#define BUFSZ 36864  // one double-buffer slot: A[128][72] + B[128][72] f16

typedef _Float16 f16;
typedef _Float16 f16x8 __attribute__((ext_vector_type(8)));
typedef float f32x4 __attribute__((ext_vector_type(4)));

// r5-proven activation numerics (libm expf/tanhf). DO NOT replace with __expf:
// fp16-amplified activation noise flips resample argsort near-ties (r6-r8).
__device__ __forceinline__ float fsig(float x){ return 1.0f/(1.0f+expf(-x)); }

__device__ __forceinline__ float brsum512(float v, float* red){
  int tid = threadIdx.x;
  red[tid]=v; __syncthreads();
  for (int s=256; s>0; s>>=1){ if (tid<s) red[tid]+=red[tid+s]; __syncthreads(); }
  float r = red[0]; __syncthreads(); return r;
}
__device__ __forceinline__ float brsum(float v, float* red){
  int tid = threadIdx.x;
  red[tid]=v; __syncthreads();
  for (int s=128; s>0; s>>=1){ if (tid<s) red[tid]+=red[tid+s]; __syncthreads(); }
  float r = red[0]; __syncthreads(); return r;
}

// gate-row remap: jhat = y*128 + q*32 + m  <->  source row = q*256 + y*32 + m
__device__ __forceinline__ int gsrow(int jp){
  return ((jp>>5)&3)*NH + (jp>>7)*32 + (jp&31);
}

// ---------- prep kernels ----------
__global__ void k_prep_w(const float* __restrict__ Whh0, const float* __restrict__ Wih1,
                         const float* __restrict__ Whh1, const float* __restrict__ b1,
                         f16* __restrict__ W0i, f16* __restrict__ W1c, float* __restrict__ b1i){
  int jp = blockIdx.x; int srow = gsrow(jp); int t = threadIdx.x;
  W0i[(size_t)jp*NH + t]        = (f16)Whh0[(size_t)srow*NH + t];
  W1c[(size_t)jp*512 + t]       = (f16)Wih1[(size_t)srow*NH + t];
  W1c[(size_t)jp*512 + 256 + t] = (f16)Whh1[(size_t)srow*NH + t];
  if (t==0) b1i[jp] = b1[srow];
}
__global__ void k_prep_xw0(const float* __restrict__ x, const float* __restrict__ Wih0,
                           const float* __restrict__ b0, float* __restrict__ xW0){
  int row = blockIdx.x; // b*16+t
  __shared__ float xr[DIN];
  if (threadIdx.x < DIN) xr[threadIdx.x] = x[(size_t)row*DIN + threadIdx.x];
  __syncthreads();
  int n = threadIdx.x;
  for (int q=0;q<4;++q){
    int wrow = q*NH + n;
    float acc = b0[wrow];
    #pragma unroll 8
    for (int d=0; d<DIN; ++d) acc += xr[d] * Wih0[(size_t)wrow*DIN + d];
    int jhat = (n>>5)*128 + q*32 + (n&31);
    xW0[(size_t)row*GW + jhat] = acc;
  }
}

// unpack particles, chain = b*256 + i, via LDS transpose (coalesced both sides)
__global__ __launch_bounds__(256) void k_init(const float* __restrict__ part,
                f16* __restrict__ h0, f16* __restrict__ h1,
                float* __restrict__ c0, float* __restrict__ c1){
  __shared__ float lh[64][65];
  __shared__ float lcv[64][65];
  int l = blockIdx.z, b = blockIdx.y;
  int i0 = (blockIdx.x >> 2)*64, n0 = (blockIdx.x & 3)*64;
  int tid = threadIdx.x;
  #pragma unroll
  for (int rep=0; rep<16; ++rep){
    int nn = rep*4 + (tid>>6);
    int ii = tid & 63;
    size_t rowb = ((size_t)(l*BSN + b)*NH + n0 + nn)*NP;
    lh[nn][ii]  = part[rowb + i0 + ii];
    lcv[nn][ii] = part[rowb + MIDP + i0 + ii];
  }
  __syncthreads();
  f16* h = l ? h1 : h0;
  float* c = l ? c1 : c0;
  #pragma unroll
  for (int rep=0; rep<16; ++rep){
    int ii = rep*4 + (tid>>6);
    int nn = tid & 63;
    size_t chain = (size_t)b*256 + i0 + ii;
    h[chain*NH + n0 + nn] = (f16)lh[nn][ii];
    c[chain*NH + n0 + nn] = lcv[nn][ii];
  }
}

// ---------- fused step: z=0 -> cfgA, z=1 -> cfgB; double-buffered staging ----------
struct StepCfg {
  const f16* A1; const f16* A2;
  float* C; f16* Hout;
  int layer; int t; int is_last;
};

__global__ __launch_bounds__(256) void k_step2(
    StepCfg cfgA, StepCfg cfgB,
    const f16* __restrict__ W0i, const f16* __restrict__ W1c,
    const float* __restrict__ xw0, const float* __restrict__ b1i,
    float* __restrict__ pr, const float* __restrict__ eps_h, const float* __restrict__ eps_c,
    const float* __restrict__ qp, const float* __restrict__ ep)
{
  __shared__ __align__(16) char smem[2*BUFSZ];   // 72 KB double buffer

  const StepCfg cfg = blockIdx.z ? cfgB : cfgA;
  const int layer  = cfg.layer;
  const int Kt     = layer ? 512 : 256;
  const int nslice = layer ? 8 : 4;
  const f16* W     = layer ? W1c : W0i;

  const int tid = threadIdx.x;
  const int lane = tid & 63, wid = tid >> 6;
  const int lr = lane >> 4, lc = lane & 15;
  const int wm = wid * 32;
  const int m0 = blockIdx.x * 128;
  const int y  = blockIdx.y;          // element cols nglob in [y*32, y*32+32)
  const int bb = blockIdx.x >> 1;     // chain = b*256+i  ->  b uniform per block

  // prefetch C state (16 regs, consumed in epilogue)
  float cold[2][2][4];
  #pragma unroll
  for (int mi=0; mi<2; ++mi)
    #pragma unroll
    for (int mh=0; mh<2; ++mh)
      #pragma unroll
      for (int r=0; r<4; ++r)
        cold[mi][mh][r] = cfg.C[(size_t)(m0 + wm + mi*16 + lr*4 + r)*NH + y*32 + mh*16 + lc];

  f32x4 acc[2][8];
  #pragma unroll
  for (int mi=0;mi<2;++mi)
    #pragma unroll
    for (int ni=0;ni<8;++ni) acc[mi][ni] = (f32x4){0.f,0.f,0.f,0.f};

  const int srow = tid >> 1, sseg = (tid & 1)*32;

  float4 ra0,ra1,ra2,ra3, rb0,rb1,rb2,rb3;
  auto loadslice = [&](int ks){
    const f16* Ab; int ka;
    if (layer==1 && ks>=4){ Ab = cfg.A2; ka = (ks-4)*64; } else { Ab = cfg.A1; ka = ks*64; }
    const float4* sa = (const float4*)(Ab + (size_t)(m0+srow)*NH + ka + sseg);
    const float4* sb = (const float4*)(W + (size_t)(y*128+srow)*Kt + (size_t)ks*64 + sseg);
    ra0=sa[0]; ra1=sa[1]; ra2=sa[2]; ra3=sa[3];
    rb0=sb[0]; rb1=sb[1]; rb2=sb[2]; rb3=sb[3];
  };
  auto writeslice = [&](int buf){
    f16* base = (f16*)(smem + buf*BUFSZ);
    float4* da = (float4*)(base + srow*72 + sseg);
    da[0]=ra0; da[1]=ra1; da[2]=ra2; da[3]=ra3;
    float4* db = (float4*)(base + 128*72 + srow*72 + sseg);
    db[0]=rb0; db[1]=rb1; db[2]=rb2; db[3]=rb3;
  };

  loadslice(0);
  writeslice(0);
  __syncthreads();
  for (int ks=0; ks<nslice; ++ks){
    const int cur = ks & 1;
    const bool more = (ks+1) < nslice;
    if (more) loadslice(ks+1);            // global loads issue; wait lands at writeslice
    const f16* bufA = (const f16*)(smem + cur*BUFSZ);
    const f16* bufB = bufA + 128*72;
    #pragma unroll
    for (int k2=0;k2<2;++k2){
      const int koff = k2*32 + lr*8;
      f16x8 a0 = *(const f16x8*)(bufA + (wm +  0 + lc)*72 + koff);
      f16x8 a1 = *(const f16x8*)(bufA + (wm + 16 + lc)*72 + koff);
      f16x8 b[8];
      #pragma unroll
      for (int ni=0;ni<8;++ni) b[ni] = *(const f16x8*)(bufB + (ni*16 + lc)*72 + koff);
      #pragma unroll
      for (int ni=0;ni<8;++ni){
        acc[0][ni] = __builtin_amdgcn_mfma_f32_16x16x32_f16(a0, b[ni], acc[0][ni], 0,0,0);
        acc[1][ni] = __builtin_amdgcn_mfma_f32_16x16x32_f16(a1, b[ni], acc[1][ni], 0,0,0);
      }
    }
    if (more) writeslice(cur ^ 1);        // other buffer: safe, last read ended at ks-1 barrier
    __syncthreads();
  }

  // per-element adds: all 4 gates of one element live in this lane (ni = 2q+mh)
  float addv[4][2];
  {
    const float* ar = (layer==0) ? (xw0 + (size_t)(bb*TTN + cfg.t)*GW + y*128)
                                 : (b1i + y*128);
    #pragma unroll
    for (int q=0;q<4;++q)
      #pragma unroll
      for (int mh=0;mh<2;++mh)
        addv[q][mh] = ar[q*32 + mh*16 + lc];
  }

  float sq=0.f, se=0.f;
  float* prstage = (float*)smem;   // [32][PRS] overlay (reused after MFMA)
  if (cfg.is_last){
    sq = sqrtf(qp[0]*qp[0]); se = sqrtf(ep[0]*ep[0]);
  }

  #pragma unroll
  for (int mi=0;mi<2;++mi)
   #pragma unroll
   for (int mh=0;mh<2;++mh)
    #pragma unroll
    for (int r=0;r<4;++r){
      float gi = acc[mi][mh+0][r] + addv[0][mh];
      float gf = acc[mi][mh+2][r] + addv[1][mh];
      float gg = acc[mi][mh+4][r] + addv[2][mh];
      float go = acc[mi][mh+6][r] + addv[3][mh];
      float c2 = fsig(gf)*cold[mi][mh][r] + fsig(gi)*tanhf(gg);
      float h2 = fsig(go)*tanhf(c2);
      int ml = wm + mi*16 + lr*4 + r;
      int chain = m0 + ml;
      int nglob = y*32 + mh*16 + lc;
      cfg.Hout[(size_t)chain*NH + nglob] = (f16)h2;
      if (!cfg.is_last){
        cfg.C[(size_t)chain*NH + nglob] = c2;
      } else {
        int ip = (blockIdx.x & 1)*128 + ml;
        size_t eidx = ((size_t)(ip*LSN + layer)*BSN + bb)*NH + nglob;
        int nl = mh*16 + lc;
        prstage[nl*PRS + ml]       = h2 + sq*eps_h[eidx];
        prstage[nl*PRS + 128 + ml] = c2 + se*eps_c[eidx];
      }
    }

  if (cfg.is_last){
    __syncthreads();
    #pragma unroll
    for (int s=0;s<8;++s){
      int u = s*256 + tid;
      int nl = u >> 6, within = u & 63;
      int half = within >> 5, q4 = within & 31;
      size_t rowp = (size_t)(layer*BSN + bb)*NH + y*32 + nl;
      float4 v = *(const float4*)(prstage + nl*PRS + half*128 + q4*4);
      *(float4*)(pr + rowp*NP + half*MIDP + (blockIdx.x & 1)*128 + q4*4) = v;
    }
  }
}

// ---------- post kernels ----------
// fused obs + stats1: 16 blocks x 512 threads; reductions bitwise == r9's order
__global__ void k_obs_stats(const float* __restrict__ pr, const float* __restrict__ Wh,
                            const float* __restrict__ bh, const float* __restrict__ wts,
                            const float* __restrict__ yv, const float* __restrict__ rp,
                            float* __restrict__ Y, float* __restrict__ pre){
  int b = blockIdx.x; int N = threadIdx.x;   // 512 threads
  __shared__ float red[512];
  float acc = bh[0];
  for (int n=0;n<NH;++n) acc += Wh[n] * pr[((size_t)(BSN + b)*NH + n)*NP + N];
  Y[(size_t)b*NP + N] = acc;
  float lw = logf(wts[b*NP+N]);
  float SW = brsum512(lw, red);
  float SY = brsum512(acc*lw, red);
  float mu = SY/SW;
  float cen = acc-mu;
  float SC = brsum512(cen*cen, red);
  float sig = SC/511.0f + rp[0]*rp[0];
  float a = sig+1e-6f, inv = 1.0f/a, ld = logf(a);
  float i0 = yv[b] - acc*lw/SW;
  pre[b*NP+N] = lw - 0.5f*ld - 0.5f*inv*i0*i0;
}

__global__ void k_colsoftmax(const float* __restrict__ pre, float* __restrict__ neww){
  int N = blockIdx.x*256 + threadIdx.x;
  float s=0.f;
  for(int b=0;b<BSN;b++) s += expf(pre[b*NP+N]);
  float ls = logf(s);
  for(int b=0;b<BSN;b++) neww[b*NP+N] = expf(pre[b*NP+N] - ls);
}

// resample + Yf gather fused
__global__ void k_resample(const float* __restrict__ neww, const float* __restrict__ gum,
                           const float* __restrict__ Y,
                           float* __restrict__ wf, int* __restrict__ idxb, int* __restrict__ dofl,
                           float* __restrict__ Yf, float* __restrict__ out){
  int b = blockIdx.x >> 1, hf = blockIdx.x & 1, j = threadIdx.x;
  __shared__ float red[256]; __shared__ float key[256]; __shared__ int sidx[256];
  float wh = neww[b*NP + hf*256 + j];
  red[j] = wh*wh; __syncthreads();
  for (int s=128;s>0;s>>=1){ if(j<s) red[j]+=red[j+s]; __syncthreads(); }
  float s2 = red[0]; __syncthreads();
  int doit = (1.0f/s2) < (float)(NP)/4.0f;
  float soft = 0.5f*wh + (0.5f/(float)MIDP);
  float kk = logf(soft) + gum[(b*2+hf)*256 + j];
  key[j] = kk; __syncthreads();
  int rank = 0;
  for (int m=0;m<256;++m){ float km = key[m]; rank += (km > kk) || (km == kk && m < j); }
  sidx[rank] = j; __syncthreads();
  idxb[(b*2+hf)*256 + j] = sidx[j];
  int N = hf*256 + j;
  int dcol = doit ? hf*256 + sidx[j] : N;
  Yf[b*NP + N] = Y[b*NP + dcol];
  float lw = logf(wh/soft);
  red[j] = lw; __syncthreads();
  for (int s=128;s>0;s>>=1){ if(j<s) red[j] = fmaxf(red[j],red[j+s]); __syncthreads(); }
  float mx = red[0]; __syncthreads();
  red[j] = expf(lw-mx); __syncthreads();
  for (int s=128;s>0;s>>=1){ if(j<s) red[j]+=red[j+s]; __syncthreads(); }
  float lse = mx + logf(red[0]);
  float wr = expf(lw - lse);
  float wv = doit ? wr : wh;
  wf[b*NP + N] = wv;
  out[4194336 + b*NP + N] = wv;
  if (j==0) dofl[b*2+hf] = doit;
}

// pf gather: 128 blocks x 256 threads, gather map cached in LDS, 64 rows/block
__global__ void k_pfg(const float* __restrict__ pr, const int* __restrict__ idxb,
                      const int* __restrict__ dofl, float* __restrict__ out){
  __shared__ int dcol[512];
  int blk = blockIdx.x;
  int q = blk & 3, lb = blk >> 2;   // lb = l*16+b
  int b = lb & 15;
  int tid = threadIdx.x;
  #pragma unroll
  for (int hf=0; hf<2; ++hf){
    int N = hf*256 + tid;
    dcol[N] = dofl[b*2+hf] ? hf*256 + idxb[(b*2+hf)*256 + tid] : N;
  }
  __syncthreads();
  int d0 = dcol[tid], d1 = dcol[tid+256];
  size_t rowbase = (size_t)lb*NH + q*64;
  for (int rr=0; rr<64; ++rr){
    size_t row = rowbase + rr;
    const float* src = pr + row*NP;
    float* dst = out + 32 + row*NP;
    dst[tid]     = src[d0];
    dst[tid+256] = src[d1];
  }
}

__global__ void k_final_est(const float* __restrict__ Yf, const float* __restrict__ wf,
                            const float* __restrict__ yv, const float* __restrict__ rp,
                            float* __restrict__ qf, float* __restrict__ ldb,
                            float* __restrict__ out){
  int b = blockIdx.x, tid = threadIdx.x;
  __shared__ float red[256];
  float w0 = wf[b*NP+tid], w1 = wf[b*NP+256+tid];
  float y0 = Yf[b*NP+tid], y1 = Yf[b*NP+256+tid];
  float SW = brsum(w0+w1, red);
  float SY = brsum(y0*w0+y1*w1, red);
  float mu = SY/SW;
  float c0=y0-mu, c1=y1-mu;
  float SC = brsum(c0*c0+c1*c1, red);
  float sig = SC/511.0f + rp[0]*rp[0];
  if (tid==0){
    float a = sig + 1e-6f; float inv = 1.0f/a; float ld = logf(a);
    float inn = yv[b]-mu; float q = inn*inn*inv;
    qf[b]=q; ldb[b]=ld;
    out[b]      = mu;
    out[16 + b] = sig;
  }
}

__global__ void k_final_scalar(const float* __restrict__ qf, const float* __restrict__ ldb,
                               float* __restrict__ out){
  if (threadIdx.x==0){
    float l=0.f, nq=0.f;
    for(int b=0;b<BSN;b++){ l += -0.5f*ldb[b]-0.5f*qf[b]; nq += qf[b]; }
    out[4202528] = l;
    out[4202529] = nq/16.0f;
  }
}

extern "C" void kernel_launch(void* const* d_in, const int* in_sizes, int n_in,
                              void* d_out, int out_size, void* d_ws, size_t ws_size,
                              hipStream_t stream) {
  const float* x      = (const float*)d_in[0];
  const float* yv     = (const float*)d_in[1];
  const float* part   = (const float*)d_in[2];
  const float* wts    = (const float*)d_in[3];
  const float* qp     = (const float*)d_in[4];
  const float* ep     = (const float*)d_in[5];
  const float* rp     = (const float*)d_in[6];
  const float* Wih0   = (const float*)d_in[7];
  const float* Whh0   = (const float*)d_in[8];
  const float* b0     = (const float*)d_in[9];
  const float* Wih1   = (const float*)d_in[10];
  const float* Whh1   = (const float*)d_in[11];
  const float* b1     = (const float*)d_in[12];
  const float* Wh     = (const float*)d_in[13];
  const float* bh     = (const float*)d_in[14];
  const float* eps_h  = (const float*)d_in[15];
  const float* eps_c  = (const float*)d_in[16];
  const float* gum    = (const float*)d_in[17];
  float* out = (float*)d_out;

  char* p = (char*)d_ws;
  f16*   W0i  = (f16*)p;  p += (size_t)GW*NH*2;
  f16*   W1c  = (f16*)p;  p += (size_t)GW*512*2;
  float* b1i  = (float*)p; p += (size_t)GW*4;
  float* xW0  = (float*)p; p += (size_t)256*GW*4;
  f16*   h0A  = (f16*)p;  p += (size_t)NCH*NH*2;
  f16*   h0B  = (f16*)p;  p += (size_t)NCH*NH*2;
  f16*   h1A  = (f16*)p;  p += (size_t)NCH*NH*2;
  f16*   h1B  = (f16*)p;  p += (size_t)NCH*NH*2;
  float* c0   = (float*)p; p += (size_t)NCH*NH*4;
  float* c1   = (float*)p; p += (size_t)NCH*NH*4;
  float* pr   = (float*)p; p += (size_t)LSN*BSN*NH*NP*4;
  float* Yb   = (float*)p; p += 32768;
  float* pre  = (float*)p; p += 32768;
  float* neww = (float*)p; p += 32768;
  float* wf   = (float*)p; p += 32768;
  float* Yf   = (float*)p; p += 32768;
  int*   idxb = (int*)p;   p += 32768;
  int*   dofl = (int*)p;   p += 128;
  float* qf   = (float*)p; p += 64;
  float* ldb  = (float*)p; p += 64;

  k_prep_w  <<<1024, 256, 0, stream>>>(Whh0, Wih1, Whh1, b1, W0i, W1c, b1i);
  k_prep_xw0<<<256, 256, 0, stream>>>(x, Wih0, b0, xW0);
  k_init    <<<dim3(16,16,2), 256, 0, stream>>>(part, h0A, h1A, c0, c1);

  // step 0, layer 0 only
  {
    StepCfg s0{h0A, nullptr, c0, h0B, 0, 0, 0};
    k_step2<<<dim3(32,8,1), 256, 0, stream>>>(s0, s0, W0i, W1c, xW0, b1i,
        pr, eps_h, eps_c, qp, ep);
  }
  f16 *h0cur=h0B, *h0nxt=h0A, *h1cur=h1A, *h1nxt=h1B;
  for (int t=0; t<15; ++t){
    StepCfg ca{h0cur, nullptr, c0, h0nxt, 0, t+1, (t+1==15) ? 1 : 0}; // layer0 step t+1
    StepCfg cb{h0cur, h1cur,   c1, h1nxt, 1, t,   0};                 // layer1 step t
    k_step2<<<dim3(32,8,2), 256, 0, stream>>>(ca, cb, W0i, W1c, xW0, b1i,
        pr, eps_h, eps_c, qp, ep);
    f16* tmp = h0cur; h0cur = h0nxt; h0nxt = tmp;
    tmp = h1cur; h1cur = h1nxt; h1nxt = tmp;
  }
  // final: layer 1, t=15
  {
    StepCfg fin{h0cur, h1cur, c1, h1nxt, 1, 15, 1};
    k_step2<<<dim3(32,8,1), 256, 0, stream>>>(fin, fin, W0i, W1c, xW0, b1i,
        pr, eps_h, eps_c, qp, ep);
  }

  k_obs_stats <<<16, 512, 0, stream>>>(pr, Wh, bh, wts, yv, rp, Yb, pre);
  k_colsoftmax<<<2, 256, 0, stream>>>(pre, neww);
  k_resample  <<<32, 256, 0, stream>>>(neww, gum, Yb, wf, idxb, dofl, Yf, out);
  k_pfg       <<<128, 256, 0, stream>>>(pr, idxb, dofl, out);
  k_final_est <<<16, 256, 0, stream>>>(Yf, wf, yv, rp, qf, ldb, out);
  k_final_scalar<<<1, 64, 0, stream>>>(qf, ldb, out);
}

// Round 11
// 390.865 us; speedup vs baseline: 29.6258x; 1.0251x over previous
//
#include <hip/hip_runtime.h>
#include <hip/hip_bf16.h>
#include <math.h>

#define LSN 2
#define BSN 16
#define NH 256
#define NP 512
#define MIDP 256
#define TTN 16
#define DIN 64
#define NCH 4096
#define GW 1024
#define PRS 268   // prstage LDS row stride (floats)
#define BUFSZ 36864  // one double-buffer slot: A[128][72] + B[128][72] f16

typedef _Float16 f16;
typedef _Float16 f16x8 __attribute__((ext_vector_type(8)));
typedef float f32x4 __attribute__((ext_vector_type(4)));

// r5-proven activation numerics (libm expf/tanhf). DO NOT replace with __expf:
// fp16-amplified activation noise flips resample argsort near-ties (r6-r8).
__device__ __forceinline__ float fsig(float x){ return 1.0f/(1.0f+expf(-x)); }

__device__ __forceinline__ float brsum512(float v, float* red){
  int tid = threadIdx.x;
  red[tid]=v; __syncthreads();
  for (int s=256; s>0; s>>=1){ if (tid<s) red[tid]+=red[tid+s]; __syncthreads(); }
  float r = red[0]; __syncthreads(); return r;
}
__device__ __forceinline__ float brsum(float v, float* red){
  int tid = threadIdx.x;
  red[tid]=v; __syncthreads();
  for (int s=128; s>0; s>>=1){ if (tid<s) red[tid]+=red[tid+s]; __syncthreads(); }
  float r = red[0]; __syncthreads(); return r;
}

// gate-row remap: jhat = y*128 + q*32 + m  <->  source row = q*256 + y*32 + m
__device__ __forceinline__ int gsrow(int jp){
  return ((jp>>5)&3)*NH + (jp>>7)*32 + (jp&31);
}

// ---------- fused prep: [0,1024) weights, [1024,1280) xW0, [1280,1792) init ----------
__global__ __launch_bounds__(256) void k_prep_all(
    const float* __restrict__ Whh0, const float* __restrict__ Wih1,
    const float* __restrict__ Whh1, const float* __restrict__ b1,
    const float* __restrict__ x, const float* __restrict__ Wih0,
    const float* __restrict__ b0, const float* __restrict__ part,
    f16* __restrict__ W0i, f16* __restrict__ W1c, float* __restrict__ b1i,
    float* __restrict__ xW0,
    f16* __restrict__ h0, f16* __restrict__ h1,
    float* __restrict__ c0, float* __restrict__ c1)
{
  __shared__ float lh[64][65];
  __shared__ float lcv[64][65];
  int bid = blockIdx.x;
  int tid = threadIdx.x;
  if (bid < 1024){
    int jp = bid; int srow = gsrow(jp); int t = tid;
    W0i[(size_t)jp*NH + t]        = (f16)Whh0[(size_t)srow*NH + t];
    W1c[(size_t)jp*512 + t]       = (f16)Wih1[(size_t)srow*NH + t];
    W1c[(size_t)jp*512 + 256 + t] = (f16)Whh1[(size_t)srow*NH + t];
    if (t==0) b1i[jp] = b1[srow];
  } else if (bid < 1280){
    int row = bid - 1024; // b*16+t
    float* xr = lh[0];
    if (tid < DIN) xr[tid] = x[(size_t)row*DIN + tid];
    __syncthreads();
    int n = tid;
    for (int q=0;q<4;++q){
      int wrow = q*NH + n;
      float acc = b0[wrow];
      #pragma unroll 8
      for (int d=0; d<DIN; ++d) acc += xr[d] * Wih0[(size_t)wrow*DIN + d];
      int jhat = (n>>5)*128 + q*32 + (n&31);
      xW0[(size_t)row*GW + jhat] = acc;
    }
  } else {
    int idx = bid - 1280;          // [0,512)
    int xb = idx & 15, b = (idx>>4)&15, l = idx>>8;
    int i0 = (xb >> 2)*64, n0 = (xb & 3)*64;
    #pragma unroll
    for (int rep=0; rep<16; ++rep){
      int nn = rep*4 + (tid>>6);
      int ii = tid & 63;
      size_t rowb = ((size_t)(l*BSN + b)*NH + n0 + nn)*NP;
      lh[nn][ii]  = part[rowb + i0 + ii];
      lcv[nn][ii] = part[rowb + MIDP + i0 + ii];
    }
    __syncthreads();
    f16* h = l ? h1 : h0;
    float* c = l ? c1 : c0;
    #pragma unroll
    for (int rep=0; rep<16; ++rep){
      int ii = rep*4 + (tid>>6);
      int nn = tid & 63;
      size_t chain = (size_t)b*256 + i0 + ii;
      h[chain*NH + n0 + nn] = (f16)lh[nn][ii];
      c[chain*NH + n0 + nn] = lcv[nn][ii];
    }
  }
}

// ---------- fused step, XCD-affine 1D grid ----------
// bid -> xcd=bid&7, j=bid>>3; mloc=j&3, y=(j>>2)&7, z=(j>>5)&1
// m-tile = xcd*4+mloc: all blocks touching rows of one m-tile share an XCD,
// so H written at step t is local-L2 for step t+1 (consistent bid%8 mapping).
struct StepCfg {
  const f16* A1; const f16* A2;
  float* C; f16* Hout;
  int layer; int t; int is_last;
};

__global__ __launch_bounds__(256) void k_step2(
    StepCfg cfgA, StepCfg cfgB,
    const f16* __restrict__ W0i, const f16* __restrict__ W1c,
    const float* __restrict__ xw0, const float* __restrict__ b1i,
    float* __restrict__ pr, const float* __restrict__ eps_h, const float* __restrict__ eps_c,
    const float* __restrict__ qp, const float* __restrict__ ep)
{
  __shared__ __align__(16) char smem[2*BUFSZ];   // 72 KB double buffer

  const int bid = blockIdx.x;
  const int xcd = bid & 7, jj = bid >> 3;
  const int mloc = jj & 3, y = (jj >> 2) & 7, z = (jj >> 5) & 1;
  const int mt = xcd*4 + mloc;         // m-tile 0..31
  const int m0 = mt * 128;

  const StepCfg cfg = z ? cfgB : cfgA;
  const int layer  = cfg.layer;
  const int Kt     = layer ? 512 : 256;
  const int nslice = layer ? 8 : 4;
  const f16* W     = layer ? W1c : W0i;

  const int tid = threadIdx.x;
  const int lane = tid & 63, wid = tid >> 6;
  const int lr = lane >> 4, lc = lane & 15;
  const int wm = wid * 32;
  const int bb = mt >> 1;              // chain = b*256+i -> b uniform per block

  // prefetch C state (16 regs, consumed in epilogue)
  float cold[2][2][4];
  #pragma unroll
  for (int mi=0; mi<2; ++mi)
    #pragma unroll
    for (int mh=0; mh<2; ++mh)
      #pragma unroll
      for (int r=0; r<4; ++r)
        cold[mi][mh][r] = cfg.C[(size_t)(m0 + wm + mi*16 + lr*4 + r)*NH + y*32 + mh*16 + lc];

  f32x4 acc[2][8];
  #pragma unroll
  for (int mi=0;mi<2;++mi)
    #pragma unroll
    for (int ni=0;ni<8;++ni) acc[mi][ni] = (f32x4){0.f,0.f,0.f,0.f};

  const int srow = tid >> 1, sseg = (tid & 1)*32;

  float4 ra0,ra1,ra2,ra3, rb0,rb1,rb2,rb3;
  auto loadslice = [&](int ks){
    const f16* Ab; int ka;
    if (layer==1 && ks>=4){ Ab = cfg.A2; ka = (ks-4)*64; } else { Ab = cfg.A1; ka = ks*64; }
    const float4* sa = (const float4*)(Ab + (size_t)(m0+srow)*NH + ka + sseg);
    const float4* sb = (const float4*)(W + (size_t)(y*128+srow)*Kt + (size_t)ks*64 + sseg);
    ra0=sa[0]; ra1=sa[1]; ra2=sa[2]; ra3=sa[3];
    rb0=sb[0]; rb1=sb[1]; rb2=sb[2]; rb3=sb[3];
  };
  auto writeslice = [&](int buf){
    f16* base = (f16*)(smem + buf*BUFSZ);
    float4* da = (float4*)(base + srow*72 + sseg);
    da[0]=ra0; da[1]=ra1; da[2]=ra2; da[3]=ra3;
    float4* db = (float4*)(base + 128*72 + srow*72 + sseg);
    db[0]=rb0; db[1]=rb1; db[2]=rb2; db[3]=rb3;
  };

  loadslice(0);
  writeslice(0);
  __syncthreads();
  for (int ks=0; ks<nslice; ++ks){
    const int cur = ks & 1;
    const bool more = (ks+1) < nslice;
    if (more) loadslice(ks+1);
    const f16* bufA = (const f16*)(smem + cur*BUFSZ);
    const f16* bufB = bufA + 128*72;
    #pragma unroll
    for (int k2=0;k2<2;++k2){
      const int koff = k2*32 + lr*8;
      f16x8 a0 = *(const f16x8*)(bufA + (wm +  0 + lc)*72 + koff);
      f16x8 a1 = *(const f16x8*)(bufA + (wm + 16 + lc)*72 + koff);
      f16x8 b[8];
      #pragma unroll
      for (int ni=0;ni<8;++ni) b[ni] = *(const f16x8*)(bufB + (ni*16 + lc)*72 + koff);
      #pragma unroll
      for (int ni=0;ni<8;++ni){
        acc[0][ni] = __builtin_amdgcn_mfma_f32_16x16x32_f16(a0, b[ni], acc[0][ni], 0,0,0);
        acc[1][ni] = __builtin_amdgcn_mfma_f32_16x16x32_f16(a1, b[ni], acc[1][ni], 0,0,0);
      }
    }
    if (more) writeslice(cur ^ 1);
    __syncthreads();
  }

  // per-element adds: all 4 gates of one element live in this lane (ni = 2q+mh)
  float addv[4][2];
  {
    const float* ar = (layer==0) ? (xw0 + (size_t)(bb*TTN + cfg.t)*GW + y*128)
                                 : (b1i + y*128);
    #pragma unroll
    for (int q=0;q<4;++q)
      #pragma unroll
      for (int mh=0;mh<2;++mh)
        addv[q][mh] = ar[q*32 + mh*16 + lc];
  }

  float sq=0.f, se=0.f;
  float* prstage = (float*)smem;   // [32][PRS] overlay (buffer 0; last slice read buffer 1)
  if (cfg.is_last){
    sq = sqrtf(qp[0]*qp[0]); se = sqrtf(ep[0]*ep[0]);
  }

  #pragma unroll
  for (int mi=0;mi<2;++mi)
   #pragma unroll
   for (int mh=0;mh<2;++mh)
    #pragma unroll
    for (int r=0;r<4;++r){
      float gi = acc[mi][mh+0][r] + addv[0][mh];
      float gf = acc[mi][mh+2][r] + addv[1][mh];
      float gg = acc[mi][mh+4][r] + addv[2][mh];
      float go = acc[mi][mh+6][r] + addv[3][mh];
      float c2 = fsig(gf)*cold[mi][mh][r] + fsig(gi)*tanhf(gg);
      float h2 = fsig(go)*tanhf(c2);
      int ml = wm + mi*16 + lr*4 + r;
      int chain = m0 + ml;
      int nglob = y*32 + mh*16 + lc;
      cfg.Hout[(size_t)chain*NH + nglob] = (f16)h2;
      if (!cfg.is_last){
        cfg.C[(size_t)chain*NH + nglob] = c2;
      } else {
        int ip = (mt & 1)*128 + ml;
        size_t eidx = ((size_t)(ip*LSN + layer)*BSN + bb)*NH + nglob;
        int nl = mh*16 + lc;
        prstage[nl*PRS + ml]       = h2 + sq*eps_h[eidx];
        prstage[nl*PRS + 128 + ml] = c2 + se*eps_c[eidx];
      }
    }

  if (cfg.is_last){
    __syncthreads();
    #pragma unroll
    for (int s=0;s<8;++s){
      int u = s*256 + tid;
      int nl = u >> 6, within = u & 63;
      int half = within >> 5, q4 = within & 31;
      size_t rowp = (size_t)(layer*BSN + bb)*NH + y*32 + nl;
      float4 v = *(const float4*)(prstage + nl*PRS + half*128 + q4*4);
      *(float4*)(pr + rowp*NP + half*MIDP + (mt & 1)*128 + q4*4) = v;
    }
  }
}

// ---------- post kernels ----------
__global__ void k_obs_stats(const float* __restrict__ pr, const float* __restrict__ Wh,
                            const float* __restrict__ bh, const float* __restrict__ wts,
                            const float* __restrict__ yv, const float* __restrict__ rp,
                            float* __restrict__ Y, float* __restrict__ pre){
  int b = blockIdx.x; int N = threadIdx.x;   // 512 threads
  __shared__ float red[512];
  float acc = bh[0];
  for (int n=0;n<NH;++n) acc += Wh[n] * pr[((size_t)(BSN + b)*NH + n)*NP + N];
  Y[(size_t)b*NP + N] = acc;
  float lw = logf(wts[b*NP+N]);
  float SW = brsum512(lw, red);
  float SY = brsum512(acc*lw, red);
  float mu = SY/SW;
  float cen = acc-mu;
  float SC = brsum512(cen*cen, red);
  float sig = SC/511.0f + rp[0]*rp[0];
  float a = sig+1e-6f, inv = 1.0f/a, ld = logf(a);
  float i0 = yv[b] - acc*lw/SW;
  pre[b*NP+N] = lw - 0.5f*ld - 0.5f*inv*i0*i0;
}

// resample (+ colsoftmax recompute, bitwise-identical b-order) + Yf gather
__global__ void k_resample(const float* __restrict__ pre, const float* __restrict__ gum,
                           const float* __restrict__ Y,
                           float* __restrict__ wf, int* __restrict__ idxb, int* __restrict__ dofl,
                           float* __restrict__ Yf, float* __restrict__ out){
  int b = blockIdx.x >> 1, hf = blockIdx.x & 1, j = threadIdx.x;
  __shared__ float red[256]; __shared__ float key[256]; __shared__ int sidx[256];
  int N = hf*256 + j;
  float s=0.f;
  for(int b2=0;b2<BSN;b2++) s += expf(pre[b2*NP+N]);
  float ls = logf(s);
  float wh = expf(pre[b*NP+N] - ls);
  red[j] = wh*wh; __syncthreads();
  for (int s2i=128;s2i>0;s2i>>=1){ if(j<s2i) red[j]+=red[j+s2i]; __syncthreads(); }
  float s2 = red[0]; __syncthreads();
  int doit = (1.0f/s2) < (float)(NP)/4.0f;
  float soft = 0.5f*wh + (0.5f/(float)MIDP);
  float kk = logf(soft) + gum[(b*2+hf)*256 + j];
  key[j] = kk; __syncthreads();
  int rank = 0;
  for (int m=0;m<256;++m){ float km = key[m]; rank += (km > kk) || (km == kk && m < j); }
  sidx[rank] = j; __syncthreads();
  idxb[(b*2+hf)*256 + j] = sidx[j];
  int dcol = doit ? hf*256 + sidx[j] : N;
  Yf[b*NP + N] = Y[b*NP + dcol];
  float lw = logf(wh/soft);
  red[j] = lw; __syncthreads();
  for (int s2i=128;s2i>0;s2i>>=1){ if(j<s2i) red[j] = fmaxf(red[j],red[j+s2i]); __syncthreads(); }
  float mx = red[0]; __syncthreads();
  red[j] = expf(lw-mx); __syncthreads();
  for (int s2i=128;s2i>0;s2i>>=1){ if(j<s2i) red[j]+=red[j+s2i]; __syncthreads(); }
  float lse = mx + logf(red[0]);
  float wr = expf(lw - lse);
  float wv = doit ? wr : wh;
  wf[b*NP + N] = wv;
  out[4194336 + b*NP + N] = wv;
  if (j==0) dofl[b*2+hf] = doit;
}

// pf gather: 128 blocks x 256 threads, gather map cached in LDS, 64 rows/block
__global__ void k_pfg(const float* __restrict__ pr, const int* __restrict__ idxb,
                      const int* __restrict__ dofl, float* __restrict__ out){
  __shared__ int dcol[512];
  int blk = blockIdx.x;
  int q = blk & 3, lb = blk >> 2;   // lb = l*16+b
  int b = lb & 15;
  int tid = threadIdx.x;
  #pragma unroll
  for (int hf=0; hf<2; ++hf){
    int N = hf*256 + tid;
    dcol[N] = dofl[b*2+hf] ? hf*256 + idxb[(b*2+hf)*256 + tid] : N;
  }
  __syncthreads();
  int d0 = dcol[tid], d1 = dcol[tid+256];
  size_t rowbase = (size_t)lb*NH + q*64;
  for (int rr=0; rr<64; ++rr){
    size_t row = rowbase + rr;
    const float* src = pr + row*NP;
    float* dst = out + 32 + row*NP;
    dst[tid]     = src[d0];
    dst[tid+256] = src[d1];
  }
}

__global__ void k_final_est(const float* __restrict__ Yf, const float* __restrict__ wf,
                            const float* __restrict__ yv, const float* __restrict__ rp,
                            float* __restrict__ qf, float* __restrict__ ldb,
                            float* __restrict__ out){
  int b = blockIdx.x, tid = threadIdx.x;
  __shared__ float red[256];
  float w0 = wf[b*NP+tid], w1 = wf[b*NP+256+tid];
  float y0 = Yf[b*NP+tid], y1 = Yf[b*NP+256+tid];
  float SW = brsum(w0+w1, red);
  float SY = brsum(y0*w0+y1*w1, red);
  float mu = SY/SW;
  float c0=y0-mu, c1=y1-mu;
  float SC = brsum(c0*c0+c1*c1, red);
  float sig = SC/511.0f + rp[0]*rp[0];
  if (tid==0){
    float a = sig + 1e-6f; float inv = 1.0f/a; float ld = logf(a);
    float inn = yv[b]-mu; float q = inn*inn*inv;
    qf[b]=q; ldb[b]=ld;
    out[b]      = mu;
    out[16 + b] = sig;
  }
}

__global__ void k_final_scalar(const float* __restrict__ qf, const float* __restrict__ ldb,
                               float* __restrict__ out){
  if (threadIdx.x==0){
    float l=0.f, nq=0.f;
    for(int b=0;b<BSN;b++){ l += -0.5f*ldb[b]-0.5f*qf[b]; nq += qf[b]; }
    out[4202528] = l;
    out[4202529] = nq/16.0f;
  }
}

extern "C" void kernel_launch(void* const* d_in, const int* in_sizes, int n_in,
                              void* d_out, int out_size, void* d_ws, size_t ws_size,
                              hipStream_t stream) {
  const float* x      = (const float*)d_in[0];
  const float* yv     = (const float*)d_in[1];
  const float* part   = (const float*)d_in[2];
  const float* wts    = (const float*)d_in[3];
  const float* qp     = (const float*)d_in[4];
  const float* ep     = (const float*)d_in[5];
  const float* rp     = (const float*)d_in[6];
  const float* Wih0   = (const float*)d_in[7];
  const float* Whh0   = (const float*)d_in[8];
  const float* b0     = (const float*)d_in[9];
  const float* Wih1   = (const float*)d_in[10];
  const float* Whh1   = (const float*)d_in[11];
  const float* b1     = (const float*)d_in[12];
  const float* Wh     = (const float*)d_in[13];
  const float* bh     = (const float*)d_in[14];
  const float* eps_h  = (const float*)d_in[15];
  const float* eps_c  = (const float*)d_in[16];
  const float* gum    = (const float*)d_in[17];
  float* out = (float*)d_out;

  char* p = (char*)d_ws;
  f16*   W0i  = (f16*)p;  p += (size_t)GW*NH*2;
  f16*   W1c  = (f16*)p;  p += (size_t)GW*512*2;
  float* b1i  = (float*)p; p += (size_t)GW*4;
  float* xW0  = (float*)p; p += (size_t)256*GW*4;
  f16*   h0A  = (f16*)p;  p += (size_t)NCH*NH*2;
  f16*   h0B  = (f16*)p;  p += (size_t)NCH*NH*2;
  f16*   h1A  = (f16*)p;  p += (size_t)NCH*NH*2;
  f16*   h1B  = (f16*)p;  p += (size_t)NCH*NH*2;
  float* c0   = (float*)p; p += (size_t)NCH*NH*4;
  float* c1   = (float*)p; p += (size_t)NCH*NH*4;
  float* pr   = (float*)p; p += (size_t)LSN*BSN*NH*NP*4;
  float* Yb   = (float*)p; p += 32768;
  float* pre  = (float*)p; p += 32768;
  float* wf   = (float*)p; p += 32768;
  float* Yf   = (float*)p; p += 32768;
  int*   idxb = (int*)p;   p += 32768;
  int*   dofl = (int*)p;   p += 128;
  float* qf   = (float*)p; p += 64;
  float* ldb  = (float*)p; p += 64;

  k_prep_all<<<1792, 256, 0, stream>>>(Whh0, Wih1, Whh1, b1, x, Wih0, b0, part,
                                       W0i, W1c, b1i, xW0, h0A, h1A, c0, c1);

  // step 0, layer 0 only (256 blocks -> z decodes to 0)
  {
    StepCfg s0{h0A, nullptr, c0, h0B, 0, 0, 0};
    k_step2<<<256, 256, 0, stream>>>(s0, s0, W0i, W1c, xW0, b1i,
        pr, eps_h, eps_c, qp, ep);
  }
  f16 *h0cur=h0B, *h0nxt=h0A, *h1cur=h1A, *h1nxt=h1B;
  for (int t=0; t<15; ++t){
    StepCfg ca{h0cur, nullptr, c0, h0nxt, 0, t+1, (t+1==15) ? 1 : 0}; // layer0 step t+1
    StepCfg cb{h0cur, h1cur,   c1, h1nxt, 1, t,   0};                 // layer1 step t
    k_step2<<<512, 256, 0, stream>>>(ca, cb, W0i, W1c, xW0, b1i,
        pr, eps_h, eps_c, qp, ep);
    f16* tmp = h0cur; h0cur = h0nxt; h0nxt = tmp;
    tmp = h1cur; h1cur = h1nxt; h1nxt = tmp;
  }
  // final: layer 1, t=15 (256 blocks, cfgA)
  {
    StepCfg fin{h0cur, h1cur, c1, h1nxt, 1, 15, 1};
    k_step2<<<256, 256, 0, stream>>>(fin, fin, W0i, W1c, xW0, b1i,
        pr, eps_h, eps_c, qp, ep);
  }

  k_obs_stats <<<16, 512, 0, stream>>>(pr, Wh, bh, wts, yv, rp, Yb, pre);
  k_resample  <<<32, 256, 0, stream>>>(pre, gum, Yb, wf, idxb, dofl, Yf, out);
  k_pfg       <<<128, 256, 0, stream>>>(pr, idxb, dofl, out);
  k_final_est <<<16, 256, 0, stream>>>(Yf, wf, yv, rp, qf, ldb, out);
  k_final_scalar<<<1, 64, 0, stream>>>(qf, ldb, out);
}